// Round 1
// 2158.341 us; speedup vs baseline: 1.5443x; 1.5443x over previous
//
#include <hip/hip_runtime.h>
#include <hip/hip_bf16.h>

// CAMixer forward, MI355X. Round 5: LDS-tiled depthwise conv rewrite.
// k_dwconv5 was latency-bound (3200 scalar 2B global loads/thread, VALUBusy 12%,
// HBM 4.4%). New structure: block = (b,c)-plane x 32-row strip, uint4-staged
// LDS tile with zero-padded columns, 1 col/thread x 32 row accumulators.
// Rest identical to passing round 4.

typedef __hip_bfloat16 bf16;
using short8 = __attribute__((ext_vector_type(8))) short;   // 8 bf16 = 4 VGPR
using f32x4  = __attribute__((ext_vector_type(4))) float;   // MFMA C/D

#define HWP 65536   // H*W
#define NB  4       // batch
#define LB  __launch_bounds__(256)

__device__ __forceinline__ float u2f(unsigned short s) {
    return __uint_as_float(((unsigned int)s) << 16);
}
__device__ __forceinline__ float b2f(bf16 v) { return __bfloat162float(v); }
__device__ __forceinline__ unsigned short f2bu(float x) {
    bf16 h = __float2bfloat16(x);
    return *reinterpret_cast<unsigned short*>(&h);
}
__device__ __forceinline__ float leaky(float x) { return x > 0.f ? x : 0.2f * x; }
__device__ __forceinline__ float sigmoidf(float x) { return 1.f / (1.f + __expf(-x)); }

__device__ __forceinline__ void ld8(const float* p, float* f) {
    float4 u0 = *reinterpret_cast<const float4*>(p);
    float4 u1 = *reinterpret_cast<const float4*>(p + 4);
    f[0] = u0.x; f[1] = u0.y; f[2] = u0.z; f[3] = u0.w;
    f[4] = u1.x; f[5] = u1.y; f[6] = u1.z; f[7] = u1.w;
}
__device__ __forceinline__ void ld8(const bf16* p, float* f) {
    uint4 u = *reinterpret_cast<const uint4*>(p);
    const unsigned short* s = reinterpret_cast<const unsigned short*>(&u);
#pragma unroll
    for (int i = 0; i < 8; i++) f[i] = u2f(s[i]);
}
__device__ __forceinline__ void st8(bf16* p, const float* f) {
    uint4 r;
    r.x = (unsigned)f2bu(f[0]) | ((unsigned)f2bu(f[1]) << 16);
    r.y = (unsigned)f2bu(f[2]) | ((unsigned)f2bu(f[3]) << 16);
    r.z = (unsigned)f2bu(f[4]) | ((unsigned)f2bu(f[5]) << 16);
    r.w = (unsigned)f2bu(f[6]) | ((unsigned)f2bu(f[7]) << 16);
    *reinterpret_cast<uint4*>(p) = r;
}
__device__ __forceinline__ void stv4(float* p, float a, float b, float c, float d) {
    float4 v; v.x = a; v.y = b; v.z = c; v.w = d;
    *reinterpret_cast<float4*>(p) = v;
}
__device__ __forceinline__ void stv4(bf16* p, float a, float b, float c, float d) {
    uint2 r;
    r.x = (unsigned)f2bu(a) | ((unsigned)f2bu(b) << 16);
    r.y = (unsigned)f2bu(c) | ((unsigned)f2bu(d) << 16);
    *reinterpret_cast<uint2*>(p) = r;
}

// ---------------------------------------------------------------------------
// 1x1 conv, 128ch -> 128ch, pixel-major. Tile 64 px x 128 oc / block.
// ---------------------------------------------------------------------------
template <typename InT, typename OutT>
__global__ LB void k_conv1x1(const InT* __restrict__ in, const float* __restrict__ w,
                             const float* __restrict__ bias, OutT* __restrict__ out) {
    __shared__ float Wt[128][128];  // Wt[k][oc]
    __shared__ float Xs[32][64];
    const int tid = threadIdx.x;
    const int p0 = blockIdx.x * 64;
    const int b = blockIdx.y;
    for (int i = tid; i < 16384; i += 256) {
        int k = i >> 7, oc = i & 127;
        Wt[k][oc] = w[oc * 128 + k];
    }
    const int pg = tid & 15;
    const int og = tid >> 4;
    float acc[4][8];
#pragma unroll
    for (int i = 0; i < 4; i++)
#pragma unroll
        for (int j = 0; j < 8; j++) acc[i][j] = 0.f;
    const InT* inb = in + ((size_t)b * 128) * HWP + p0;
    for (int k0 = 0; k0 < 128; k0 += 32) {
        __syncthreads();
        {
            int row = tid >> 3;
            int col0 = (tid & 7) * 8;
            float t8[8];
            ld8(inb + (size_t)(k0 + row) * HWP + col0, t8);
#pragma unroll
            for (int i = 0; i < 8; i++) Xs[row][col0 + i] = t8[i];
        }
        __syncthreads();
#pragma unroll
        for (int kk = 0; kk < 32; kk++) {
            float a0 = Xs[kk][pg * 4 + 0];
            float a1 = Xs[kk][pg * 4 + 1];
            float a2 = Xs[kk][pg * 4 + 2];
            float a3 = Xs[kk][pg * 4 + 3];
            const float* wr = &Wt[k0 + kk][og * 8];
#pragma unroll
            for (int j = 0; j < 8; j++) {
                float wv = wr[j];
                acc[0][j] += a0 * wv;
                acc[1][j] += a1 * wv;
                acc[2][j] += a2 * wv;
                acc[3][j] += a3 * wv;
            }
        }
    }
#pragma unroll
    for (int j = 0; j < 8; j++) {
        int oc = og * 8 + j;
        float bv = bias[oc];
        OutT* po = out + ((size_t)(b * 128 + oc)) * HWP + p0 + pg * 4;
        stv4(po, acc[0][j] + bv, acc[1][j] + bv, acc[2][j] + bv, acc[3][j] + bv);
    }
}

// ---------------------------------------------------------------------------
// rin: f = leaky(conv1x1(cond)); cond = [v(128) | cond_global | cy | cx]
// ---------------------------------------------------------------------------
__global__ LB void k_rin(const float* __restrict__ v, const float* __restrict__ cg,
                         const float* __restrict__ w, const float* __restrict__ bias,
                         float* __restrict__ f) {
    __shared__ float Wl[131][36];
    __shared__ float Bs[32];
    const int tid = threadIdx.x;
    for (int i = tid; i < 131 * 32; i += 256) {
        int ic = i >> 5, oc = i & 31;
        Wl[ic][oc] = w[oc * 131 + ic];
    }
    if (tid < 32) Bs[tid] = bias[tid];
    __syncthreads();
    const int p = blockIdx.x * 256 + tid;
    const int b = blockIdx.y;
    float acc[32];
#pragma unroll
    for (int o = 0; o < 32; o++) acc[o] = 0.f;
    const float* vb = v + ((size_t)b * 128) * HWP + p;
    for (int ic = 0; ic < 128; ic++) {
        float a = vb[(size_t)ic * HWP];
#pragma unroll
        for (int o = 0; o < 32; o++) acc[o] += a * Wl[ic][o];
    }
    float a128 = cg[(size_t)b * HWP + p];
    int y = p >> 8, x = p & 255;
    float a129 = -1.f + (2.f / 15.f) * (float)(y & 15);
    float a130 = -1.f + (2.f / 15.f) * (float)(x & 15);
#pragma unroll
    for (int o = 0; o < 32; o++) {
        float r = acc[o] + a128 * Wl[128][o] + a129 * Wl[129][o] + a130 * Wl[130][o] + Bs[o];
        f[((size_t)(b * 32 + o)) * HWP + p] = leaky(r);
    }
}

// offsets = conv1x1(leaky(conv1x1(f))): 32 -> 16 -> 2
__global__ LB void k_offsets(const float* __restrict__ f, const float* __restrict__ w1,
                             const float* __restrict__ b1, const float* __restrict__ w2,
                             const float* __restrict__ b2, float* __restrict__ offs) {
    __shared__ float W1[32][16];
    __shared__ float W2[16][2];
    __shared__ float B1[16];
    __shared__ float B2[2];
    const int tid = threadIdx.x;
    for (int i = tid; i < 512; i += 256) {
        int ic = i >> 4, o = i & 15;
        W1[ic][o] = w1[o * 32 + ic];
    }
    if (tid < 32) { int h = tid >> 1, o = tid & 1; W2[h][o] = w2[o * 16 + h]; }
    if (tid < 16) B1[tid] = b1[tid];
    if (tid < 2) B2[tid] = b2[tid];
    __syncthreads();
    const int p = blockIdx.x * 256 + tid;
    const int b = blockIdx.y;
    float h[16];
#pragma unroll
    for (int o = 0; o < 16; o++) h[o] = B1[o];
    for (int ic = 0; ic < 32; ic++) {
        float a = f[((size_t)(b * 32 + ic)) * HWP + p];
#pragma unroll
        for (int o = 0; o < 16; o++) h[o] += a * W1[ic][o];
    }
    float o0 = B2[0], o1 = B2[1];
#pragma unroll
    for (int o = 0; o < 16; o++) {
        float hv = leaky(h[o]);
        o0 += hv * W2[o][0];
        o1 += hv * W2[o][1];
    }
    offs[((size_t)(b * 2 + 0)) * HWP + p] = o0;
    offs[((size_t)(b * 2 + 1)) * HWP + p] = o1;
}

__global__ LB void k_fpix(const float* __restrict__ f, float* __restrict__ fpix) {
    const int p = blockIdx.x * 256 + threadIdx.x;
    const int b = blockIdx.y;
    float s = 0.f;
    for (int c = 0; c < 32; c++) s += f[((size_t)(b * 32 + c)) * HWP + p];
    fpix[(size_t)b * HWP + p] = s * (1.f / 32.f);
}

__global__ LB void k_fmean(const float* __restrict__ f, float* __restrict__ fmean) {
    const int b = blockIdx.x >> 5, c = blockIdx.x & 31;
    const float* base = f + ((size_t)(b * 32 + c)) * HWP;
    float s = 0.f;
    for (int i = threadIdx.x; i < HWP; i += 256) s += base[i];
    __shared__ float red[256];
    red[threadIdx.x] = s;
    __syncthreads();
    for (int st = 128; st > 0; st >>= 1) {
        if (threadIdx.x < st) red[threadIdx.x] += red[threadIdx.x + st];
        __syncthreads();
    }
    if (threadIdx.x == 0) fmean[b * 32 + c] = red[0];
}

__global__ LB void k_ca(const float* __restrict__ fmean, const float* __restrict__ w,
                        const float* __restrict__ bias, float* __restrict__ ca) {
    const int b = blockIdx.x, oc = threadIdx.x;
    float acc = bias[oc];
    for (int ic = 0; ic < 32; ic++)
        acc += w[oc * 32 + ic] * fmean[b * 32 + ic] * (1.f / 65536.f);
    ca[b * 128 + oc] = sigmoidf(acc);
}

__global__ LB void k_sa(const float* __restrict__ f, const float* __restrict__ w,
                        const float* __restrict__ bias, float* __restrict__ sa) {
    __shared__ float Wl[32][9];
    __shared__ float bs;
    const int tid = threadIdx.x;
    for (int i = tid; i < 288; i += 256) Wl[i / 9][i % 9] = w[i];
    if (tid == 0) bs = bias[0];
    __syncthreads();
    const int p = blockIdx.x * 256 + tid;
    const int b = blockIdx.y;
    const int y = p >> 8, x = p & 255;
    float acc = bs;
    for (int ic = 0; ic < 32; ic++) {
        const float* fb = f + ((size_t)(b * 32 + ic)) * HWP;
#pragma unroll
        for (int dy = 0; dy < 3; dy++) {
            int yy = y + dy - 1;
            if ((unsigned)yy >= 256u) continue;
#pragma unroll
            for (int dx = 0; dx < 3; dx++) {
                int xx = x + dx - 1;
                if ((unsigned)xx >= 256u) continue;
                acc += fb[yy * 256 + xx] * Wl[ic][dy * 3 + dx];
            }
        }
    }
    sa[(size_t)b * HWP + p] = sigmoidf(acc);
}

// gumbel hard mask per window; thread = window
__global__ LB void k_mask(const float* __restrict__ fpix, const float* __restrict__ gum,
                          const float* __restrict__ w1, const float* __restrict__ b1,
                          const float* __restrict__ w2, const float* __restrict__ b2,
                          float* __restrict__ mask) {
    __shared__ float W1[256][16];
    __shared__ float W2[2][16];
    __shared__ float B1[16];
    __shared__ float B2[2];
    const int tid = threadIdx.x;
    for (int i = tid; i < 4096; i += 256) {
        int o = i >> 8, e = i & 255;
        W1[e][o] = w1[o * 256 + e];
    }
    if (tid < 32) W2[tid >> 4][tid & 15] = w2[tid];
    if (tid < 16) B1[tid] = b1[tid];
    if (tid < 2) B2[tid] = b2[tid];
    __syncthreads();
    const int wid = blockIdx.x * 256 + tid;
    const int b = wid >> 8, n = wid & 255;
    const int wy = n >> 4, wx = n & 15;
    const float* fp = fpix + (size_t)b * HWP + (wy * 16) * 256 + wx * 16;
    float h[16];
#pragma unroll
    for (int o = 0; o < 16; o++) h[o] = B1[o];
    for (int e = 0; e < 256; e++) {
        float mv = fp[(e >> 4) * 256 + (e & 15)];
#pragma unroll
        for (int o = 0; o < 16; o++) h[o] += mv * W1[e][o];
    }
    float l0 = B2[0], l1 = B2[1];
#pragma unroll
    for (int o = 0; o < 16; o++) {
        float hv = leaky(h[o]);
        l0 += hv * W2[0][o];
        l1 += hv * W2[1][o];
    }
    float mx = fmaxf(l0, l1);
    float e0 = __expf(l0 - mx), e1 = __expf(l1 - mx);
    float inv = 1.f / (e0 + e1);
    float p0 = e0 * inv, p1 = e1 * inv;
    float u0 = gum[wid * 2 + 0], u1 = gum[wid * 2 + 1];
    float g0 = -logf(-logf(u0 + 1e-10f) + 1e-10f);
    float g1 = -logf(-logf(u1 + 1e-10f) + 1e-10f);
    mask[wid] = (p0 + g0 >= p1 + g1) ? 1.f : 0.f;
}

// bilinear flow warp, border clamp; bf16 out
__global__ LB void k_warp(const float* __restrict__ x, const float* __restrict__ offs,
                          bf16* __restrict__ xw) {
    const int p = blockIdx.x * 256 + threadIdx.x;
    const int b = blockIdx.y;
    const int y = p >> 8, xc = p & 255;
    float fx = offs[((size_t)(b * 2 + 0)) * HWP + p];
    float fy = offs[((size_t)(b * 2 + 1)) * HWP + p];
    float sx = fminf(fmaxf((float)xc + fx, 0.f), 255.f);
    float sy = fminf(fmaxf((float)y + fy, 0.f), 255.f);
    float x0f = floorf(sx), y0f = floorf(sy);
    float wx = sx - x0f, wy = sy - y0f;
    int x0 = (int)x0f, y0 = (int)y0f;
    int x1 = min(x0 + 1, 255), y1 = min(y0 + 1, 255);
    float w00 = (1.f - wx) * (1.f - wy), w01 = wx * (1.f - wy);
    float w10 = (1.f - wx) * wy, w11 = wx * wy;
    const int i00 = y0 * 256 + x0, i01 = y0 * 256 + x1;
    const int i10 = y1 * 256 + x0, i11 = y1 * 256 + x1;
    const float* xb = x + ((size_t)b * 128) * HWP;
    bf16* ob = xw + ((size_t)b * 128) * HWP + p;
    for (int c = 0; c < 128; c++) {
        const float* cb = xb + (size_t)c * HWP;
        float val = cb[i00] * w00 + cb[i01] * w01 + cb[i10] * w10 + cb[i11] * w11;
        ob[(size_t)c * HWP] = __float2bfloat16(val);
    }
}

// ---------------------------------------------------------------------------
// q/k projection: token-major out q[wid*256+t][128] bf16, skip mask==0 windows
// ---------------------------------------------------------------------------
__global__ LB void k_qkproj(const bf16* __restrict__ xw, const float* __restrict__ w,
                            const float* __restrict__ bias, const float* __restrict__ mask,
                            bf16* __restrict__ outq) {
    const int blk = blockIdx.x;
    const int wid = blk >> 2;
    if (mask[wid] < 0.5f) return;  // block-uniform
    const int b = wid >> 8, n = wid & 255;
    const int wy = n >> 4, wx = n & 15;
    const int t0 = (blk & 3) * 64;
    __shared__ float Wt[128][128];
    __shared__ float Xs[32][64];
    const int tid = threadIdx.x;
    for (int i = tid; i < 16384; i += 256) {
        int k = i >> 7, oc = i & 127;
        Wt[k][oc] = w[oc * 128 + k];
    }
    const int pg = tid & 15;
    const int og = tid >> 4;
    float acc[4][8];
#pragma unroll
    for (int i = 0; i < 4; i++)
#pragma unroll
        for (int j = 0; j < 8; j++) acc[i][j] = 0.f;
    const bf16* inb = xw + ((size_t)b * 128) * HWP;
    const int pixbase = (wy * 16) * 256 + wx * 16;
    for (int k0 = 0; k0 < 128; k0 += 32) {
        __syncthreads();
        {
            int row = tid >> 3;
            int col0 = (tid & 7) * 8;
            int tt = t0 + col0;
            float t8[8];
            ld8(inb + (size_t)(k0 + row) * HWP + pixbase + (tt >> 4) * 256 + (tt & 15), t8);
#pragma unroll
            for (int i = 0; i < 8; i++) Xs[row][col0 + i] = t8[i];
        }
        __syncthreads();
#pragma unroll
        for (int kk = 0; kk < 32; kk++) {
            float a0 = Xs[kk][pg * 4 + 0];
            float a1 = Xs[kk][pg * 4 + 1];
            float a2 = Xs[kk][pg * 4 + 2];
            float a3 = Xs[kk][pg * 4 + 3];
            const float* wr = &Wt[k0 + kk][og * 8];
#pragma unroll
            for (int j = 0; j < 8; j++) {
                float wv = wr[j];
                acc[0][j] += a0 * wv;
                acc[1][j] += a1 * wv;
                acc[2][j] += a2 * wv;
                acc[3][j] += a3 * wv;
            }
        }
    }
    float bv[8];
#pragma unroll
    for (int j = 0; j < 8; j++) bv[j] = bias[og * 8 + j];
#pragma unroll
    for (int i = 0; i < 4; i++) {
        int tt = t0 + pg * 4 + i;
        bf16* po = outq + ((size_t)(wid * 256 + tt)) * 128 + og * 8;
        float fv[8];
#pragma unroll
        for (int j = 0; j < 8; j++) fv[j] = acc[i][j] + bv[j];
        st8(po, fv);
    }
}

// ---------------------------------------------------------------------------
// MFMA flash attention. Block = window (256 thr = 4 waves); wave w owns Q rows
// [64w, 64w+64). Online softmax over 64-col j-tiles. mfma_f32_16x16x32_bf16.
// A/B frag: lane -> [row=lane&15][k=(lane>>4)*8+j]; C/D: row=(lane>>4)*4+i,
// col=lane&15 (learn_hip m89/m120 verified layouts).
// ---------------------------------------------------------------------------
__global__ __launch_bounds__(256, 1) void k_attn(
        const bf16* __restrict__ qbuf, const bf16* __restrict__ kbuf,
        const float* __restrict__ v, const float* __restrict__ sa,
        const float* __restrict__ mask, bf16* __restrict__ wout) {
    const int wid = blockIdx.x;
    const int b = wid >> 8, n = wid & 255;
    const int wy = n >> 4, wx = n & 15;
    const int tid = threadIdx.x;
    const int pixbase = (wy * 16) * 256 + wx * 16;
    const float* vb = v + ((size_t)b * 128) * HWP;
    if (mask[wid] < 0.5f) {        // block-uniform branch
        const int t = tid;
        const int pix = pixbase + (t >> 4) * 256 + (t & 15);
        float s = sa[(size_t)b * HWP + pix];
        bf16* orow = wout + ((size_t)(wid * 256 + t)) * 128;
        for (int c0 = 0; c0 < 128; c0 += 8) {
            float fv[8];
#pragma unroll
            for (int i = 0; i < 8; i++) fv[i] = vb[(size_t)(c0 + i) * HWP + pix] * s;
            st8(orow + c0, fv);
        }
        return;
    }
    __shared__ unsigned short Pl[4][64][72];   // per-wave P relayout buffer
    __shared__ unsigned short Vt[128][72];     // V^T tile: [c][j], bf16
    const int w = tid >> 6, lane = tid & 63, quad = lane >> 4, lid = lane & 15;
    const bf16* qwin = qbuf + (size_t)wid * 256 * 128;
    const bf16* kwin = kbuf + (size_t)wid * 256 * 128;
    // resident Q fragments: rows w*64 + mt*16 + lid, k = kf*32 + quad*8 .. +7
    short8 qf[4][4];
#pragma unroll
    for (int mt = 0; mt < 4; mt++)
#pragma unroll
        for (int kf = 0; kf < 4; kf++)
            qf[mt][kf] = *reinterpret_cast<const short8*>(
                qwin + (size_t)(w * 64 + mt * 16 + lid) * 128 + kf * 32 + quad * 8);

    f32x4 O[4][8];
#pragma unroll
    for (int mt = 0; mt < 4; mt++)
#pragma unroll
        for (int cf = 0; cf < 8; cf++)
#pragma unroll
            for (int i = 0; i < 4; i++) O[mt][cf][i] = 0.f;
    float mrow[4][4], lrow[4][4];
#pragma unroll
    for (int mt = 0; mt < 4; mt++)
#pragma unroll
        for (int i = 0; i < 4; i++) { mrow[mt][i] = -1e30f; lrow[mt][i] = 0.f; }

    for (int j0 = 0; j0 < 256; j0 += 64) {
        __syncthreads();   // prev iter's Vt reads complete
        // stage V tile transposed: Vt[c][j] = v[c][token j0+j]
        {
            int c = tid >> 1, jh = (tid & 1) * 32;
            const float* vcol = vb + (size_t)c * HWP + pixbase;
#pragma unroll
            for (int jj = 0; jj < 32; jj += 2) {
                int t1 = j0 + jh + jj, t2 = t1 + 1;
                float v1 = vcol[(t1 >> 4) * 256 + (t1 & 15)];
                float v2 = vcol[(t2 >> 4) * 256 + (t2 & 15)];
                unsigned u = (unsigned)f2bu(v1) | ((unsigned)f2bu(v2) << 16);
                *reinterpret_cast<unsigned*>(&Vt[c][jh + jj]) = u;
            }
        }
        // S = Q K^T for this j-tile (overlaps V-staging latency)
        f32x4 sacc[4][4];
#pragma unroll
        for (int nt = 0; nt < 4; nt++) {
            short8 kfr[4];
#pragma unroll
            for (int kf = 0; kf < 4; kf++)
                kfr[kf] = *reinterpret_cast<const short8*>(
                    kwin + (size_t)(j0 + nt * 16 + lid) * 128 + kf * 32 + quad * 8);
#pragma unroll
            for (int mt = 0; mt < 4; mt++) {
                f32x4 acc;
                acc[0] = 0.f; acc[1] = 0.f; acc[2] = 0.f; acc[3] = 0.f;
#pragma unroll
                for (int kf = 0; kf < 4; kf++)
                    acc = __builtin_amdgcn_mfma_f32_16x16x32_bf16(qf[mt][kf], kfr[kf], acc, 0, 0, 0);
                sacc[mt][nt] = acc;
            }
        }
        // online softmax update (rows = mt*16 + quad*4 + i; 16-lane row groups)
        float alpha[4][4];
#pragma unroll
        for (int mt = 0; mt < 4; mt++)
#pragma unroll
            for (int i = 0; i < 4; i++) {
                float mx = sacc[mt][0][i];
                mx = fmaxf(mx, sacc[mt][1][i]);
                mx = fmaxf(mx, sacc[mt][2][i]);
                mx = fmaxf(mx, sacc[mt][3][i]);
                mx = fmaxf(mx, __shfl_xor(mx, 1));
                mx = fmaxf(mx, __shfl_xor(mx, 2));
                mx = fmaxf(mx, __shfl_xor(mx, 4));
                mx = fmaxf(mx, __shfl_xor(mx, 8));
                float mn = fmaxf(mrow[mt][i], mx);
                alpha[mt][i] = __expf(mrow[mt][i] - mn);
                mrow[mt][i] = mn;
            }
        // P = exp(S - m), row sums, write P (bf16) to per-wave LDS
#pragma unroll
        for (int mt = 0; mt < 4; mt++) {
            float ps[4] = {0.f, 0.f, 0.f, 0.f};
#pragma unroll
            for (int nt = 0; nt < 4; nt++)
#pragma unroll
                for (int i = 0; i < 4; i++) {
                    float p = __expf(sacc[mt][nt][i] - mrow[mt][i]);
                    ps[i] += p;
                    Pl[w][mt * 16 + quad * 4 + i][nt * 16 + lid] = f2bu(p);
                }
#pragma unroll
            for (int i = 0; i < 4; i++) {
                float rs = ps[i];
                rs += __shfl_xor(rs, 1);
                rs += __shfl_xor(rs, 2);
                rs += __shfl_xor(rs, 4);
                rs += __shfl_xor(rs, 8);
                lrow[mt][i] = lrow[mt][i] * alpha[mt][i] + rs;
            }
        }
        // rescale O
#pragma unroll
        for (int mt = 0; mt < 4; mt++)
#pragma unroll
            for (int cf = 0; cf < 8; cf++)
#pragma unroll
                for (int i = 0; i < 4; i++) O[mt][cf][i] *= alpha[mt][i];
        __syncthreads();   // Vt staged (cross-wave), Pl written
        // O += P V   (A = P rows, B = Vt rows = channels)
        short8 pa[4][2];
#pragma unroll
        for (int mt = 0; mt < 4; mt++)
#pragma unroll
            for (int kq = 0; kq < 2; kq++)
                pa[mt][kq] = *reinterpret_cast<const short8*>(
                    &Pl[w][mt * 16 + lid][kq * 32 + quad * 8]);
#pragma unroll
        for (int cf = 0; cf < 8; cf++) {
            short8 vf0 = *reinterpret_cast<const short8*>(&Vt[cf * 16 + lid][quad * 8]);
            short8 vf1 = *reinterpret_cast<const short8*>(&Vt[cf * 16 + lid][32 + quad * 8]);
#pragma unroll
            for (int mt = 0; mt < 4; mt++) {
                O[mt][cf] = __builtin_amdgcn_mfma_f32_16x16x32_bf16(pa[mt][0], vf0, O[mt][cf], 0, 0, 0);
                O[mt][cf] = __builtin_amdgcn_mfma_f32_16x16x32_bf16(pa[mt][1], vf1, O[mt][cf], 0, 0, 0);
            }
        }
    }
    // epilogue: divide by l, store (C-layout scatter, 2B stores)
#pragma unroll
    for (int mt = 0; mt < 4; mt++) {
        float inv[4];
#pragma unroll
        for (int i = 0; i < 4; i++) inv[i] = 1.f / lrow[mt][i];
#pragma unroll
        for (int cf = 0; cf < 8; cf++)
#pragma unroll
            for (int i = 0; i < 4; i++) {
                int row = w * 64 + mt * 16 + quad * 4 + i;
                int col = cf * 16 + lid;
                *reinterpret_cast<unsigned short*>(
                    &wout[((size_t)(wid * 256 + row)) * 128 + col]) = f2bu(O[mt][cf][i] * inv[i]);
            }
    }
}

// window-token-major -> pixel-major (bf16 -> bf16)
__global__ LB void k_unwindow(const bf16* __restrict__ wsrc, bf16* __restrict__ dst) {
    const int p = blockIdx.x * 256 + threadIdx.x;
    const int b = blockIdx.y;
    const int y = p >> 8, x = p & 255;
    const int wid = b * 256 + (y >> 4) * 16 + (x >> 4);
    const int t = (y & 15) * 16 + (x & 15);
    const bf16* src = wsrc + ((size_t)(wid * 256 + t)) * 128;
    bf16* d = dst + ((size_t)b * 128) * HWP + p;
    for (int c0 = 0; c0 < 128; c0 += 8) {
        uint4 u = *reinterpret_cast<const uint4*>(src + c0);
        const unsigned short* s = reinterpret_cast<const unsigned short*>(&u);
#pragma unroll
        for (int i = 0; i < 8; i++)
            *reinterpret_cast<unsigned short*>(&d[(size_t)(c0 + i) * HWP]) = s[i];
    }
}

// ---------------------------------------------------------------------------
// depthwise 5x5, pad = 2*DIL, dilation DIL (bf16 -> bf16).
// Round 5 rewrite: block = one (b,c) plane x 32-row strip. Stage strip+halo
// rows into LDS via uint4 (8x bf16) loads, 8-col zero pad each side (no column
// bounds checks, 16B-aligned stores). Thread = one column, 32 fp32 row accs in
// registers; per staged row: 5 scalar LDS reads (2-way bank alias = free) feed
// up to 25 statically-indexed FMAs. Weights are block-uniform -> SGPRs.
// ---------------------------------------------------------------------------
template <int DIL>
__global__ LB void k_dwconv5(const bf16* __restrict__ in, const float* __restrict__ w,
                             const float* __restrict__ bias, bf16* __restrict__ out) {
    constexpr int HLO = 2 * DIL;          // halo rows/cols each side (2 or 6)
    constexpr int ROWS = 32;              // output rows per block
    constexpr int NR = ROWS + 2 * HLO;    // staged rows (36 or 44)
    __shared__ unsigned short Ls[NR][272];  // cols: [0..7]=pad, [8..263]=img, [264..271]=pad
    const int tid = threadIdx.x;
    const int bc = blockIdx.y;            // b*128 + c
    const int c = bc & 127;
    const int r0 = blockIdx.x * ROWS;
    const bf16* ib = in + (size_t)bc * HWP;
    // stage NR rows (zero rows out of image range)
    for (int i = tid; i < NR * 32; i += 256) {
        int row = i >> 5, seg = i & 31;
        int y = r0 - HLO + row;
        uint4 val;
        if ((unsigned)y < 256u) {
            val = *reinterpret_cast<const uint4*>(ib + y * 256 + seg * 8);
        } else {
            val.x = 0u; val.y = 0u; val.z = 0u; val.w = 0u;
        }
        *reinterpret_cast<uint4*>(&Ls[row][8 + seg * 8]) = val;
    }
    // zero the column pads
    for (int i = tid; i < NR * 2; i += 256) {
        int row = i >> 1;
        uint4 zz; zz.x = 0u; zz.y = 0u; zz.z = 0u; zz.w = 0u;
        *reinterpret_cast<uint4*>(&Ls[row][(i & 1) ? 264 : 0]) = zz;
    }
    // weights: block-uniform -> scalar loads
    float W[25];
#pragma unroll
    for (int i = 0; i < 25; i++) W[i] = w[c * 25 + i];
    const float bv = bias[c];
    __syncthreads();
    const int x = tid;                    // thread = column
    float acc[ROWS];
#pragma unroll
    for (int r = 0; r < ROWS; r++) acc[r] = bv;
#pragma unroll
    for (int iy = 0; iy < NR; iy++) {
        float v5[5];
#pragma unroll
        for (int dx = 0; dx < 5; dx++)
            v5[dx] = u2f(Ls[iy][8 + x + (dx - 2) * DIL]);
#pragma unroll
        for (int dy = 0; dy < 5; dy++) {
            const int ro = iy - HLO + (2 - dy) * DIL;   // compile-time after unroll
            if (ro < 0 || ro >= ROWS) continue;
#pragma unroll
            for (int dx = 0; dx < 5; dx++)
                acc[ro] += v5[dx] * W[dy * 5 + dx];
        }
    }
    bf16* ob = out + (size_t)bc * HWP + (size_t)r0 * 256 + x;
#pragma unroll
    for (int r = 0; r < ROWS; r++)
        *reinterpret_cast<unsigned short*>(&ob[r * 256]) = f2bu(acc[r]);
}

// out = gelu_exact(g) * ca + res   (bf16 in, bf16 out)
__global__ LB void k_tmp(const bf16* __restrict__ g, const float* __restrict__ ca,
                         const bf16* __restrict__ res, bf16* __restrict__ out) {
    const int p = blockIdx.x * 256 + threadIdx.x;
    const int b = blockIdx.y;
    for (int c = 0; c < 128; c++) {
        size_t idx = ((size_t)(b * 128 + c)) * HWP + p;
        float gv = b2f(g[idx]);
        float gl = 0.5f * gv * (1.f + erff(gv * 0.70710678118654752f));
        out[idx] = __float2bfloat16(gl * ca[b * 128 + c] + b2f(res[idx]));
    }
}

// ---------------------------------------------------------------------------
extern "C" void kernel_launch(void* const* d_in, const int* in_sizes, int n_in,
                              void* d_out, int out_size, void* d_ws, size_t ws_size,
                              hipStream_t stream) {
    const float* x     = (const float*)d_in[0];
    const float* cg    = (const float*)d_in[1];
    const float* gum   = (const float*)d_in[2];
    const float* pv_w  = (const float*)d_in[3];
    const float* pv_b  = (const float*)d_in[4];
    const float* pq_w  = (const float*)d_in[5];
    const float* pq_b  = (const float*)d_in[6];
    const float* pk_w  = (const float*)d_in[7];
    const float* pk_b  = (const float*)d_in[8];
    const float* cs1_w = (const float*)d_in[9];
    const float* cs1_b = (const float*)d_in[10];
    const float* cs2_w = (const float*)d_in[11];
    const float* cs2_b = (const float*)d_in[12];
    const float* cs3_w = (const float*)d_in[13];
    const float* cs3_b = (const float*)d_in[14];
    const float* po_w  = (const float*)d_in[15];
    const float* po_b  = (const float*)d_in[16];
    const float* rin_w = (const float*)d_in[17];
    const float* rin_b = (const float*)d_in[18];
    const float* ro1_w = (const float*)d_in[19];
    const float* ro1_b = (const float*)d_in[20];
    const float* ro2_w = (const float*)d_in[21];
    const float* ro2_b = (const float*)d_in[22];
    const float* rm1_w = (const float*)d_in[23];
    const float* rm1_b = (const float*)d_in[24];
    const float* rm2_w = (const float*)d_in[25];
    const float* rm2_b = (const float*)d_in[26];
    const float* rca_w = (const float*)d_in[27];
    const float* rca_b = (const float*)d_in[28];
    const float* rsa_w = (const float*)d_in[29];
    const float* rsa_b = (const float*)d_in[30];

    char* wsp = (char*)d_ws;
    size_t off = 0;
    auto alloc = [&](size_t bytes) -> char* {
        char* p = wsp + off;
        off += (bytes + 255) & ~(size_t)255;
        return p;
    };
    const size_t NELT = (size_t)NB * 128 * HWP;  // 33.5M elems
    float* v    = (float*)alloc(NELT * 4);                  // fp32: pv out (control path)
    float* f    = (float*)alloc((size_t)NB * 32 * HWP * 4); // fp32
    bf16*  xw   = (bf16*)alloc(NELT * 2);                   // warp out; attn wout; dw2 out
    bf16*  qb   = (bf16*)alloc(NELT * 2);                   // q; out1 (residual)
    bf16*  kb   = (bf16*)alloc(NELT * 2);                   // k; cs1 out; tmp out
    float* offs = (float*)alloc((size_t)NB * 2 * HWP * 4);
    float* sab  = (float*)alloc((size_t)NB * HWP * 4);
    float* fpix = (float*)alloc((size_t)NB * HWP * 4);
    float* fmean= (float*)alloc(NB * 32 * 4);
    float* cab  = (float*)alloc(NB * 128 * 4);
    float* mk   = (float*)alloc(NB * 256 * 4);
    bf16*  dw1o = (bf16*)v;   // v's space reused after attention (dw1 out)
    (void)ws_size; (void)in_sizes; (void)n_in; (void)out_size;

    float* out = (float*)d_out;
    dim3 gpix(256, NB);

    k_conv1x1<float, float><<<dim3(1024, NB), 256, 0, stream>>>(x, pv_w, pv_b, v);
    k_rin<<<gpix, 256, 0, stream>>>(v, cg, rin_w, rin_b, f);
    k_offsets<<<gpix, 256, 0, stream>>>(f, ro1_w, ro1_b, ro2_w, ro2_b, offs);
    k_fpix<<<gpix, 256, 0, stream>>>(f, fpix);
    k_fmean<<<dim3(NB * 32), 256, 0, stream>>>(f, fmean);
    k_ca<<<dim3(NB), 128, 0, stream>>>(fmean, rca_w, rca_b, cab);
    k_sa<<<gpix, 256, 0, stream>>>(f, rsa_w, rsa_b, sab);
    k_mask<<<dim3(NB), 256, 0, stream>>>(fpix, gum, rm1_w, rm1_b, rm2_w, rm2_b, mk);
    k_warp<<<gpix, 256, 0, stream>>>(x, offs, xw);
    k_qkproj<<<dim3(4096), 256, 0, stream>>>(xw, pq_w, pq_b, mk, qb);
    k_qkproj<<<dim3(4096), 256, 0, stream>>>(xw, pk_w, pk_b, mk, kb);
    k_attn<<<dim3(NB * 256), 256, 0, stream>>>(qb, kb, v, sab, mk, xw);
    k_unwindow<<<gpix, 256, 0, stream>>>(xw, qb);
    k_conv1x1<bf16, bf16><<<dim3(1024, NB), 256, 0, stream>>>(qb, cs1_w, cs1_b, kb);
    k_dwconv5<1><<<dim3(256 / 32, NB * 128), 256, 0, stream>>>(kb, cs2_w, cs2_b, dw1o);
    k_dwconv5<3><<<dim3(256 / 32, NB * 128), 256, 0, stream>>>(dw1o, cs3_w, cs3_b, xw);
    k_tmp<<<gpix, 256, 0, stream>>>(xw, cab, qb, kb);
    k_conv1x1<bf16, float><<<dim3(1024, NB), 256, 0, stream>>>(kb, po_w, po_b, out);
}

// Round 2
// 1341.979 us; speedup vs baseline: 2.4837x; 1.6083x over previous
//
#include <hip/hip_runtime.h>
#include <hip/hip_bf16.h>

// CAMixer forward, MI355X. Round 6: token-major smooth-path wire + MFMA GEMMs.
// k_conv1x1 (VALU fp32 GEMM, 319us x3, occupancy 11.5%) replaced:
//  - wire layout for qk/attn-out/tmp-out flipped to token-major [tok][128c]
//    so MFMA A-frags are direct contiguous 16B loads (k_attn's pattern).
//  - k_wingemm: per-window 256x128x128 MFMA GEMM (qkproj / cs1 / po modes),
//    bf16 weights staged to padded LDS [128][136], fp32 accum.
//  - k_unwindow deleted; dwconv<3> emits token-major; k_tmp fully vectorized.
//  - pv conv stays fp32 VALU (mask-path accuracy) with chunked 16KB weight LDS
//    (72KB -> 24KB block) to fix the 11.5% occupancy.

typedef __hip_bfloat16 bf16;
using short8 = __attribute__((ext_vector_type(8))) short;   // 8 bf16 = 4 VGPR
using f32x4  = __attribute__((ext_vector_type(4))) float;   // MFMA C/D

#define HWP 65536   // H*W
#define NB  4       // batch
#define LB  __launch_bounds__(256)

__device__ __forceinline__ float u2f(unsigned short s) {
    return __uint_as_float(((unsigned int)s) << 16);
}
__device__ __forceinline__ float b2f(bf16 v) { return __bfloat162float(v); }
__device__ __forceinline__ unsigned short f2bu(float x) {
    bf16 h = __float2bfloat16(x);
    return *reinterpret_cast<unsigned short*>(&h);
}
__device__ __forceinline__ float leaky(float x) { return x > 0.f ? x : 0.2f * x; }
__device__ __forceinline__ float sigmoidf(float x) { return 1.f / (1.f + __expf(-x)); }

__device__ __forceinline__ void ld8(const float* p, float* f) {
    float4 u0 = *reinterpret_cast<const float4*>(p);
    float4 u1 = *reinterpret_cast<const float4*>(p + 4);
    f[0] = u0.x; f[1] = u0.y; f[2] = u0.z; f[3] = u0.w;
    f[4] = u1.x; f[5] = u1.y; f[6] = u1.z; f[7] = u1.w;
}
__device__ __forceinline__ void ld8(const bf16* p, float* f) {
    uint4 u = *reinterpret_cast<const uint4*>(p);
    const unsigned short* s = reinterpret_cast<const unsigned short*>(&u);
#pragma unroll
    for (int i = 0; i < 8; i++) f[i] = u2f(s[i]);
}
__device__ __forceinline__ void st8(bf16* p, const float* f) {
    uint4 r;
    r.x = (unsigned)f2bu(f[0]) | ((unsigned)f2bu(f[1]) << 16);
    r.y = (unsigned)f2bu(f[2]) | ((unsigned)f2bu(f[3]) << 16);
    r.z = (unsigned)f2bu(f[4]) | ((unsigned)f2bu(f[5]) << 16);
    r.w = (unsigned)f2bu(f[6]) | ((unsigned)f2bu(f[7]) << 16);
    *reinterpret_cast<uint4*>(p) = r;
}
__device__ __forceinline__ void stv4(float* p, float a, float b, float c, float d) {
    float4 v; v.x = a; v.y = b; v.z = c; v.w = d;
    *reinterpret_cast<float4*>(p) = v;
}
__device__ __forceinline__ void stv4(bf16* p, float a, float b, float c, float d) {
    uint2 r;
    r.x = (unsigned)f2bu(a) | ((unsigned)f2bu(b) << 16);
    r.y = (unsigned)f2bu(c) | ((unsigned)f2bu(d) << 16);
    *reinterpret_cast<uint2*>(p) = r;
}

// ---------------------------------------------------------------------------
// pv: 1x1 conv fp32->fp32, pixel-major (control path; stays fp32 VALU).
// Chunked weight LDS (16KB/chunk) -> 24KB block, ~3 blocks/CU.
// ---------------------------------------------------------------------------
__global__ LB void k_pvconv(const float* __restrict__ in, const float* __restrict__ w,
                            const float* __restrict__ bias, float* __restrict__ out) {
    __shared__ float Wt[32][128];   // current k-chunk, [k][oc]
    __shared__ float Xs[32][64];
    const int tid = threadIdx.x;
    const int p0 = blockIdx.x * 64;
    const int b = blockIdx.y;
    const int pg = tid & 15;
    const int og = tid >> 4;
    float acc[4][8];
#pragma unroll
    for (int i = 0; i < 4; i++)
#pragma unroll
        for (int j = 0; j < 8; j++) acc[i][j] = 0.f;
    const float* inb = in + ((size_t)b * 128) * HWP + p0;
    for (int k0 = 0; k0 < 128; k0 += 32) {
        __syncthreads();
        // stage weight chunk: Wt[k][oc] = w[oc*128 + k0 + k]
#pragma unroll
        for (int it = 0; it < 4; it++) {
            int jj = tid + it * 256;          // [0,1024)
            int oc = jj & 127, kq = jj >> 7;  // kq 0..7
            float4 wv = *reinterpret_cast<const float4*>(w + oc * 128 + k0 + kq * 4);
            Wt[kq * 4 + 0][oc] = wv.x;
            Wt[kq * 4 + 1][oc] = wv.y;
            Wt[kq * 4 + 2][oc] = wv.z;
            Wt[kq * 4 + 3][oc] = wv.w;
        }
        // stage X chunk
        {
            int row = tid >> 3;
            int col0 = (tid & 7) * 8;
            float t8[8];
            ld8(inb + (size_t)(k0 + row) * HWP + col0, t8);
#pragma unroll
            for (int i = 0; i < 8; i++) Xs[row][col0 + i] = t8[i];
        }
        __syncthreads();
#pragma unroll
        for (int kk = 0; kk < 32; kk++) {
            float a0 = Xs[kk][pg * 4 + 0];
            float a1 = Xs[kk][pg * 4 + 1];
            float a2 = Xs[kk][pg * 4 + 2];
            float a3 = Xs[kk][pg * 4 + 3];
            const float* wr = &Wt[kk][og * 8];
#pragma unroll
            for (int j = 0; j < 8; j++) {
                float wv = wr[j];
                acc[0][j] += a0 * wv;
                acc[1][j] += a1 * wv;
                acc[2][j] += a2 * wv;
                acc[3][j] += a3 * wv;
            }
        }
    }
#pragma unroll
    for (int j = 0; j < 8; j++) {
        int oc = og * 8 + j;
        float bv = bias[oc];
        float* po = out + ((size_t)(b * 128 + oc)) * HWP + p0 + pg * 4;
        stv4(po, acc[0][j] + bv, acc[1][j] + bv, acc[2][j] + bv, acc[3][j] + bv);
    }
}

// ---------------------------------------------------------------------------
// rin: f = leaky(conv1x1(cond)); cond = [v(128) | cond_global | cy | cx]
// ---------------------------------------------------------------------------
__global__ LB void k_rin(const float* __restrict__ v, const float* __restrict__ cg,
                         const float* __restrict__ w, const float* __restrict__ bias,
                         float* __restrict__ f) {
    __shared__ float Wl[131][36];
    __shared__ float Bs[32];
    const int tid = threadIdx.x;
    for (int i = tid; i < 131 * 32; i += 256) {
        int ic = i >> 5, oc = i & 31;
        Wl[ic][oc] = w[oc * 131 + ic];
    }
    if (tid < 32) Bs[tid] = bias[tid];
    __syncthreads();
    const int p = blockIdx.x * 256 + tid;
    const int b = blockIdx.y;
    float acc[32];
#pragma unroll
    for (int o = 0; o < 32; o++) acc[o] = 0.f;
    const float* vb = v + ((size_t)b * 128) * HWP + p;
    for (int ic = 0; ic < 128; ic++) {
        float a = vb[(size_t)ic * HWP];
#pragma unroll
        for (int o = 0; o < 32; o++) acc[o] += a * Wl[ic][o];
    }
    float a128 = cg[(size_t)b * HWP + p];
    int y = p >> 8, x = p & 255;
    float a129 = -1.f + (2.f / 15.f) * (float)(y & 15);
    float a130 = -1.f + (2.f / 15.f) * (float)(x & 15);
#pragma unroll
    for (int o = 0; o < 32; o++) {
        float r = acc[o] + a128 * Wl[128][o] + a129 * Wl[129][o] + a130 * Wl[130][o] + Bs[o];
        f[((size_t)(b * 32 + o)) * HWP + p] = leaky(r);
    }
}

// offsets = conv1x1(leaky(conv1x1(f))): 32 -> 16 -> 2
__global__ LB void k_offsets(const float* __restrict__ f, const float* __restrict__ w1,
                             const float* __restrict__ b1, const float* __restrict__ w2,
                             const float* __restrict__ b2, float* __restrict__ offs) {
    __shared__ float W1[32][16];
    __shared__ float W2[16][2];
    __shared__ float B1[16];
    __shared__ float B2[2];
    const int tid = threadIdx.x;
    for (int i = tid; i < 512; i += 256) {
        int ic = i >> 4, o = i & 15;
        W1[ic][o] = w1[o * 32 + ic];
    }
    if (tid < 32) { int h = tid >> 1, o = tid & 1; W2[h][o] = w2[o * 16 + h]; }
    if (tid < 16) B1[tid] = b1[tid];
    if (tid < 2) B2[tid] = b2[tid];
    __syncthreads();
    const int p = blockIdx.x * 256 + tid;
    const int b = blockIdx.y;
    float h[16];
#pragma unroll
    for (int o = 0; o < 16; o++) h[o] = B1[o];
    for (int ic = 0; ic < 32; ic++) {
        float a = f[((size_t)(b * 32 + ic)) * HWP + p];
#pragma unroll
        for (int o = 0; o < 16; o++) h[o] += a * W1[ic][o];
    }
    float o0 = B2[0], o1 = B2[1];
#pragma unroll
    for (int o = 0; o < 16; o++) {
        float hv = leaky(h[o]);
        o0 += hv * W2[o][0];
        o1 += hv * W2[o][1];
    }
    offs[((size_t)(b * 2 + 0)) * HWP + p] = o0;
    offs[((size_t)(b * 2 + 1)) * HWP + p] = o1;
}

__global__ LB void k_fpix(const float* __restrict__ f, float* __restrict__ fpix) {
    const int p = blockIdx.x * 256 + threadIdx.x;
    const int b = blockIdx.y;
    float s = 0.f;
    for (int c = 0; c < 32; c++) s += f[((size_t)(b * 32 + c)) * HWP + p];
    fpix[(size_t)b * HWP + p] = s * (1.f / 32.f);
}

__global__ LB void k_fmean(const float* __restrict__ f, float* __restrict__ fmean) {
    const int b = blockIdx.x >> 5, c = blockIdx.x & 31;
    const float* base = f + ((size_t)(b * 32 + c)) * HWP;
    float s = 0.f;
    for (int i = threadIdx.x; i < HWP; i += 256) s += base[i];
    __shared__ float red[256];
    red[threadIdx.x] = s;
    __syncthreads();
    for (int st = 128; st > 0; st >>= 1) {
        if (threadIdx.x < st) red[threadIdx.x] += red[threadIdx.x + st];
        __syncthreads();
    }
    if (threadIdx.x == 0) fmean[b * 32 + c] = red[0];
}

__global__ LB void k_ca(const float* __restrict__ fmean, const float* __restrict__ w,
                        const float* __restrict__ bias, float* __restrict__ ca) {
    const int b = blockIdx.x, oc = threadIdx.x;
    float acc = bias[oc];
    for (int ic = 0; ic < 32; ic++)
        acc += w[oc * 32 + ic] * fmean[b * 32 + ic] * (1.f / 65536.f);
    ca[b * 128 + oc] = sigmoidf(acc);
}

__global__ LB void k_sa(const float* __restrict__ f, const float* __restrict__ w,
                        const float* __restrict__ bias, float* __restrict__ sa) {
    __shared__ float Wl[32][9];
    __shared__ float bs;
    const int tid = threadIdx.x;
    for (int i = tid; i < 288; i += 256) Wl[i / 9][i % 9] = w[i];
    if (tid == 0) bs = bias[0];
    __syncthreads();
    const int p = blockIdx.x * 256 + tid;
    const int b = blockIdx.y;
    const int y = p >> 8, x = p & 255;
    float acc = bs;
    for (int ic = 0; ic < 32; ic++) {
        const float* fb = f + ((size_t)(b * 32 + ic)) * HWP;
#pragma unroll
        for (int dy = 0; dy < 3; dy++) {
            int yy = y + dy - 1;
            if ((unsigned)yy >= 256u) continue;
#pragma unroll
            for (int dx = 0; dx < 3; dx++) {
                int xx = x + dx - 1;
                if ((unsigned)xx >= 256u) continue;
                acc += fb[yy * 256 + xx] * Wl[ic][dy * 3 + dx];
            }
        }
    }
    sa[(size_t)b * HWP + p] = sigmoidf(acc);
}

// gumbel hard mask per window; thread = window
__global__ LB void k_mask(const float* __restrict__ fpix, const float* __restrict__ gum,
                          const float* __restrict__ w1, const float* __restrict__ b1,
                          const float* __restrict__ w2, const float* __restrict__ b2,
                          float* __restrict__ mask) {
    __shared__ float W1[256][16];
    __shared__ float W2[2][16];
    __shared__ float B1[16];
    __shared__ float B2[2];
    const int tid = threadIdx.x;
    for (int i = tid; i < 4096; i += 256) {
        int o = i >> 8, e = i & 255;
        W1[e][o] = w1[o * 256 + e];
    }
    if (tid < 32) W2[tid >> 4][tid & 15] = w2[tid];
    if (tid < 16) B1[tid] = b1[tid];
    if (tid < 2) B2[tid] = b2[tid];
    __syncthreads();
    const int wid = blockIdx.x * 256 + tid;
    const int b = wid >> 8, n = wid & 255;
    const int wy = n >> 4, wx = n & 15;
    const float* fp = fpix + (size_t)b * HWP + (wy * 16) * 256 + wx * 16;
    float h[16];
#pragma unroll
    for (int o = 0; o < 16; o++) h[o] = B1[o];
    for (int e = 0; e < 256; e++) {
        float mv = fp[(e >> 4) * 256 + (e & 15)];
#pragma unroll
        for (int o = 0; o < 16; o++) h[o] += mv * W1[e][o];
    }
    float l0 = B2[0], l1 = B2[1];
#pragma unroll
    for (int o = 0; o < 16; o++) {
        float hv = leaky(h[o]);
        l0 += hv * W2[0][o];
        l1 += hv * W2[1][o];
    }
    float mx = fmaxf(l0, l1);
    float e0 = __expf(l0 - mx), e1 = __expf(l1 - mx);
    float inv = 1.f / (e0 + e1);
    float p0 = e0 * inv, p1 = e1 * inv;
    float u0 = gum[wid * 2 + 0], u1 = gum[wid * 2 + 1];
    float g0 = -logf(-logf(u0 + 1e-10f) + 1e-10f);
    float g1 = -logf(-logf(u1 + 1e-10f) + 1e-10f);
    mask[wid] = (p0 + g0 >= p1 + g1) ? 1.f : 0.f;
}

// bilinear flow warp, border clamp; TOKEN-MAJOR bf16 out: xw[(wid*256+t)][c]
__global__ LB void k_warp(const float* __restrict__ x, const float* __restrict__ offs,
                          bf16* __restrict__ xw) {
    const int p = blockIdx.x * 256 + threadIdx.x;
    const int b = blockIdx.y;
    const int y = p >> 8, xc = p & 255;
    float fx = offs[((size_t)(b * 2 + 0)) * HWP + p];
    float fy = offs[((size_t)(b * 2 + 1)) * HWP + p];
    float sx = fminf(fmaxf((float)xc + fx, 0.f), 255.f);
    float sy = fminf(fmaxf((float)y + fy, 0.f), 255.f);
    float x0f = floorf(sx), y0f = floorf(sy);
    float wx = sx - x0f, wy = sy - y0f;
    int x0 = (int)x0f, y0 = (int)y0f;
    int x1 = min(x0 + 1, 255), y1 = min(y0 + 1, 255);
    float w00 = (1.f - wx) * (1.f - wy), w01 = wx * (1.f - wy);
    float w10 = (1.f - wx) * wy, w11 = wx * wy;
    const int i00 = y0 * 256 + x0, i01 = y0 * 256 + x1;
    const int i10 = y1 * 256 + x0, i11 = y1 * 256 + x1;
    const float* xb = x + ((size_t)b * 128) * HWP;
    const int wid = b * 256 + (y >> 4) * 16 + (xc >> 4);
    const int t = (y & 15) * 16 + (xc & 15);
    bf16* ob = xw + ((size_t)(wid * 256 + t)) * 128;
    for (int c0 = 0; c0 < 128; c0 += 8) {
        float fv[8];
#pragma unroll
        for (int i = 0; i < 8; i++) {
            const float* cb = xb + (size_t)(c0 + i) * HWP;
            fv[i] = cb[i00] * w00 + cb[i01] * w01 + cb[i10] * w10 + cb[i11] * w11;
        }
        st8(ob + c0, fv);
    }
}

// ---------------------------------------------------------------------------
// MFMA per-window GEMM: out[256tok x 128oc] = A[256tok x 128k] * W^T + bias.
// A token-major bf16 (contiguous per window). Weights w[oc][k] fp32 -> bf16
// LDS [128][136] (padded, 16B-aligned rows). Frag layouts = k_attn's verified
// patterns (A: row=lane&15, k=quad*8+j; B: col=lane&15, k=quad*8+j;
// C/D: row=quad*4+i, col=lane&15).
// MODE 0: token-major bf16 out, skip masked windows (qkproj)
// MODE 1: pixel-major bf16 out (cs1)
// MODE 2: pixel-major fp32 out (po)
// ---------------------------------------------------------------------------
template <int MODE, typename OutT>
__global__ __launch_bounds__(256, 1) void k_wingemm(
        const bf16* __restrict__ A, const float* __restrict__ w,
        const float* __restrict__ bias, const float* __restrict__ mask,
        OutT* __restrict__ outp) {
    const int wid = blockIdx.x;
    if (MODE == 0) {
        if (mask[wid] < 0.5f) return;   // block-uniform
    }
    __shared__ unsigned short Wl[128][136];  // [oc][k], rows 272B (16B-mult)
    __shared__ float Bs[128];
    const int tid = threadIdx.x;
    for (int j = tid; j < 4096; j += 256) {
        int oc = j >> 5, k4 = (j & 31) * 4;
        float4 wv = *reinterpret_cast<const float4*>(w + oc * 128 + k4);
        uint2 r;
        r.x = (unsigned)f2bu(wv.x) | ((unsigned)f2bu(wv.y) << 16);
        r.y = (unsigned)f2bu(wv.z) | ((unsigned)f2bu(wv.w) << 16);
        *reinterpret_cast<uint2*>(&Wl[oc][k4]) = r;
    }
    if (tid < 128) Bs[tid] = bias[tid];
    const int wv_ = tid >> 6, lane = tid & 63, quad = lane >> 4, lid = lane & 15;
    const bf16* arow = A + (size_t)wid * 256 * 128;
    // A fragments: rows wv_*64 + mt*16 + lid, k = kf*32 + quad*8 .. +7
    short8 af[4][4];
#pragma unroll
    for (int mt = 0; mt < 4; mt++)
#pragma unroll
        for (int kf = 0; kf < 4; kf++)
            af[mt][kf] = *reinterpret_cast<const short8*>(
                arow + (size_t)(wv_ * 64 + mt * 16 + lid) * 128 + kf * 32 + quad * 8);
    __syncthreads();
    f32x4 acc[4][8];
#pragma unroll
    for (int mt = 0; mt < 4; mt++)
#pragma unroll
        for (int cf = 0; cf < 8; cf++)
#pragma unroll
            for (int i = 0; i < 4; i++) acc[mt][cf][i] = 0.f;
#pragma unroll
    for (int cf = 0; cf < 8; cf++) {
        short8 wf[4];
#pragma unroll
        for (int kf = 0; kf < 4; kf++)
            wf[kf] = *reinterpret_cast<const short8*>(&Wl[cf * 16 + lid][kf * 32 + quad * 8]);
#pragma unroll
        for (int mt = 0; mt < 4; mt++)
#pragma unroll
            for (int kf = 0; kf < 4; kf++)
                acc[mt][cf] = __builtin_amdgcn_mfma_f32_16x16x32_bf16(af[mt][kf], wf[kf], acc[mt][cf], 0, 0, 0);
    }
    // epilogue
    if (MODE == 0) {
        bf16* ob = (bf16*)outp;
#pragma unroll
        for (int cf = 0; cf < 8; cf++) {
            float bv = Bs[cf * 16 + lid];
#pragma unroll
            for (int mt = 0; mt < 4; mt++)
#pragma unroll
                for (int i = 0; i < 4; i++) {
                    int row = wv_ * 64 + mt * 16 + quad * 4 + i;
                    *reinterpret_cast<unsigned short*>(
                        &ob[((size_t)(wid * 256 + row)) * 128 + cf * 16 + lid]) =
                        f2bu(acc[mt][cf][i] + bv);
                }
        }
    } else {
        const int b = wid >> 8, n = wid & 255;
        const int wy = n >> 4, wx = n & 15;
#pragma unroll
        for (int cf = 0; cf < 8; cf++) {
            int oc = cf * 16 + lid;
            float bv = Bs[oc];
            OutT* plane = outp + ((size_t)(b * 128 + oc)) * HWP;
#pragma unroll
            for (int mt = 0; mt < 4; mt++) {
                int t0 = wv_ * 64 + mt * 16 + quad * 4;   // 4-aligned token
                int ty = t0 >> 4, tx = t0 & 15;
                int px = (wy * 16 + ty) * 256 + wx * 16 + tx;
                stv4(plane + px, acc[mt][cf][0] + bv, acc[mt][cf][1] + bv,
                     acc[mt][cf][2] + bv, acc[mt][cf][3] + bv);
            }
        }
    }
}

// ---------------------------------------------------------------------------
// MFMA flash attention (unchanged from round 4; token-major q/k in, token-major
// wout, pixel-major fp32 v).
// ---------------------------------------------------------------------------
__global__ __launch_bounds__(256, 1) void k_attn(
        const bf16* __restrict__ qbuf, const bf16* __restrict__ kbuf,
        const float* __restrict__ v, const float* __restrict__ sa,
        const float* __restrict__ mask, bf16* __restrict__ wout) {
    const int wid = blockIdx.x;
    const int b = wid >> 8, n = wid & 255;
    const int wy = n >> 4, wx = n & 15;
    const int tid = threadIdx.x;
    const int pixbase = (wy * 16) * 256 + wx * 16;
    const float* vb = v + ((size_t)b * 128) * HWP;
    if (mask[wid] < 0.5f) {        // block-uniform branch
        const int t = tid;
        const int pix = pixbase + (t >> 4) * 256 + (t & 15);
        float s = sa[(size_t)b * HWP + pix];
        bf16* orow = wout + ((size_t)(wid * 256 + t)) * 128;
        for (int c0 = 0; c0 < 128; c0 += 8) {
            float fv[8];
#pragma unroll
            for (int i = 0; i < 8; i++) fv[i] = vb[(size_t)(c0 + i) * HWP + pix] * s;
            st8(orow + c0, fv);
        }
        return;
    }
    __shared__ unsigned short Pl[4][64][72];   // per-wave P relayout buffer
    __shared__ unsigned short Vt[128][72];     // V^T tile: [c][j], bf16
    const int w = tid >> 6, lane = tid & 63, quad = lane >> 4, lid = lane & 15;
    const bf16* qwin = qbuf + (size_t)wid * 256 * 128;
    const bf16* kwin = kbuf + (size_t)wid * 256 * 128;
    short8 qf[4][4];
#pragma unroll
    for (int mt = 0; mt < 4; mt++)
#pragma unroll
        for (int kf = 0; kf < 4; kf++)
            qf[mt][kf] = *reinterpret_cast<const short8*>(
                qwin + (size_t)(w * 64 + mt * 16 + lid) * 128 + kf * 32 + quad * 8);

    f32x4 O[4][8];
#pragma unroll
    for (int mt = 0; mt < 4; mt++)
#pragma unroll
        for (int cf = 0; cf < 8; cf++)
#pragma unroll
            for (int i = 0; i < 4; i++) O[mt][cf][i] = 0.f;
    float mrow[4][4], lrow[4][4];
#pragma unroll
    for (int mt = 0; mt < 4; mt++)
#pragma unroll
        for (int i = 0; i < 4; i++) { mrow[mt][i] = -1e30f; lrow[mt][i] = 0.f; }

    for (int j0 = 0; j0 < 256; j0 += 64) {
        __syncthreads();   // prev iter's Vt reads complete
        {
            int c = tid >> 1, jh = (tid & 1) * 32;
            const float* vcol = vb + (size_t)c * HWP + pixbase;
#pragma unroll
            for (int jj = 0; jj < 32; jj += 2) {
                int t1 = j0 + jh + jj, t2 = t1 + 1;
                float v1 = vcol[(t1 >> 4) * 256 + (t1 & 15)];
                float v2 = vcol[(t2 >> 4) * 256 + (t2 & 15)];
                unsigned u = (unsigned)f2bu(v1) | ((unsigned)f2bu(v2) << 16);
                *reinterpret_cast<unsigned*>(&Vt[c][jh + jj]) = u;
            }
        }
        f32x4 sacc[4][4];
#pragma unroll
        for (int nt = 0; nt < 4; nt++) {
            short8 kfr[4];
#pragma unroll
            for (int kf = 0; kf < 4; kf++)
                kfr[kf] = *reinterpret_cast<const short8*>(
                    kwin + (size_t)(j0 + nt * 16 + lid) * 128 + kf * 32 + quad * 8);
#pragma unroll
            for (int mt = 0; mt < 4; mt++) {
                f32x4 acc;
                acc[0] = 0.f; acc[1] = 0.f; acc[2] = 0.f; acc[3] = 0.f;
#pragma unroll
                for (int kf = 0; kf < 4; kf++)
                    acc = __builtin_amdgcn_mfma_f32_16x16x32_bf16(qf[mt][kf], kfr[kf], acc, 0, 0, 0);
                sacc[mt][nt] = acc;
            }
        }
        float alpha[4][4];
#pragma unroll
        for (int mt = 0; mt < 4; mt++)
#pragma unroll
            for (int i = 0; i < 4; i++) {
                float mx = sacc[mt][0][i];
                mx = fmaxf(mx, sacc[mt][1][i]);
                mx = fmaxf(mx, sacc[mt][2][i]);
                mx = fmaxf(mx, sacc[mt][3][i]);
                mx = fmaxf(mx, __shfl_xor(mx, 1));
                mx = fmaxf(mx, __shfl_xor(mx, 2));
                mx = fmaxf(mx, __shfl_xor(mx, 4));
                mx = fmaxf(mx, __shfl_xor(mx, 8));
                float mn = fmaxf(mrow[mt][i], mx);
                alpha[mt][i] = __expf(mrow[mt][i] - mn);
                mrow[mt][i] = mn;
            }
#pragma unroll
        for (int mt = 0; mt < 4; mt++) {
            float ps[4] = {0.f, 0.f, 0.f, 0.f};
#pragma unroll
            for (int nt = 0; nt < 4; nt++)
#pragma unroll
                for (int i = 0; i < 4; i++) {
                    float p = __expf(sacc[mt][nt][i] - mrow[mt][i]);
                    ps[i] += p;
                    Pl[w][mt * 16 + quad * 4 + i][nt * 16 + lid] = f2bu(p);
                }
#pragma unroll
            for (int i = 0; i < 4; i++) {
                float rs = ps[i];
                rs += __shfl_xor(rs, 1);
                rs += __shfl_xor(rs, 2);
                rs += __shfl_xor(rs, 4);
                rs += __shfl_xor(rs, 8);
                lrow[mt][i] = lrow[mt][i] * alpha[mt][i] + rs;
            }
        }
#pragma unroll
        for (int mt = 0; mt < 4; mt++)
#pragma unroll
            for (int cf = 0; cf < 8; cf++)
#pragma unroll
                for (int i = 0; i < 4; i++) O[mt][cf][i] *= alpha[mt][i];
        __syncthreads();   // Vt staged (cross-wave), Pl written
        short8 pa[4][2];
#pragma unroll
        for (int mt = 0; mt < 4; mt++)
#pragma unroll
            for (int kq = 0; kq < 2; kq++)
                pa[mt][kq] = *reinterpret_cast<const short8*>(
                    &Pl[w][mt * 16 + lid][kq * 32 + quad * 8]);
#pragma unroll
        for (int cf = 0; cf < 8; cf++) {
            short8 vf0 = *reinterpret_cast<const short8*>(&Vt[cf * 16 + lid][quad * 8]);
            short8 vf1 = *reinterpret_cast<const short8*>(&Vt[cf * 16 + lid][32 + quad * 8]);
#pragma unroll
            for (int mt = 0; mt < 4; mt++) {
                O[mt][cf] = __builtin_amdgcn_mfma_f32_16x16x32_bf16(pa[mt][0], vf0, O[mt][cf], 0, 0, 0);
                O[mt][cf] = __builtin_amdgcn_mfma_f32_16x16x32_bf16(pa[mt][1], vf1, O[mt][cf], 0, 0, 0);
            }
        }
    }
#pragma unroll
    for (int mt = 0; mt < 4; mt++) {
        float inv[4];
#pragma unroll
        for (int i = 0; i < 4; i++) inv[i] = 1.f / lrow[mt][i];
#pragma unroll
        for (int cf = 0; cf < 8; cf++)
#pragma unroll
            for (int i = 0; i < 4; i++) {
                int row = w * 64 + mt * 16 + quad * 4 + i;
                int col = cf * 16 + lid;
                *reinterpret_cast<unsigned short*>(
                    &wout[((size_t)(wid * 256 + row)) * 128 + col]) = f2bu(O[mt][cf][i] * inv[i]);
            }
    }
}

// ---------------------------------------------------------------------------
// depthwise 5x5, pad = 2*DIL, dilation DIL (bf16 -> bf16). LDS-strip tiled.
// TOKOUT: write token-major [tok][c] (same scalar-store count as pixel-major).
// ---------------------------------------------------------------------------
template <int DIL, bool TOKOUT>
__global__ LB void k_dwconv5(const bf16* __restrict__ in, const float* __restrict__ w,
                             const float* __restrict__ bias, bf16* __restrict__ out) {
    constexpr int HLO = 2 * DIL;          // halo rows/cols each side (2 or 6)
    constexpr int ROWS = 32;              // output rows per block
    constexpr int NR = ROWS + 2 * HLO;    // staged rows (36 or 44)
    __shared__ unsigned short Ls[NR][272];  // cols: [0..7]=pad, [8..263]=img, [264..271]=pad
    const int tid = threadIdx.x;
    const int bc = blockIdx.y;            // b*128 + c
    const int c = bc & 127;
    const int r0 = blockIdx.x * ROWS;
    const bf16* ib = in + (size_t)bc * HWP;
    for (int i = tid; i < NR * 32; i += 256) {
        int row = i >> 5, seg = i & 31;
        int y = r0 - HLO + row;
        uint4 val;
        if ((unsigned)y < 256u) {
            val = *reinterpret_cast<const uint4*>(ib + y * 256 + seg * 8);
        } else {
            val.x = 0u; val.y = 0u; val.z = 0u; val.w = 0u;
        }
        *reinterpret_cast<uint4*>(&Ls[row][8 + seg * 8]) = val;
    }
    for (int i = tid; i < NR * 2; i += 256) {
        int row = i >> 1;
        uint4 zz; zz.x = 0u; zz.y = 0u; zz.z = 0u; zz.w = 0u;
        *reinterpret_cast<uint4*>(&Ls[row][(i & 1) ? 264 : 0]) = zz;
    }
    float W[25];
#pragma unroll
    for (int i = 0; i < 25; i++) W[i] = w[c * 25 + i];
    const float bv = bias[c];
    __syncthreads();
    const int x = tid;                    // thread = column
    float acc[ROWS];
#pragma unroll
    for (int r = 0; r < ROWS; r++) acc[r] = bv;
#pragma unroll
    for (int iy = 0; iy < NR; iy++) {
        float v5[5];
#pragma unroll
        for (int dx = 0; dx < 5; dx++)
            v5[dx] = u2f(Ls[iy][8 + x + (dx - 2) * DIL]);
#pragma unroll
        for (int dy = 0; dy < 5; dy++) {
            const int ro = iy - HLO + (2 - dy) * DIL;   // compile-time after unroll
            if (ro < 0 || ro >= ROWS) continue;
#pragma unroll
            for (int dx = 0; dx < 5; dx++)
                acc[ro] += v5[dx] * W[dy * 5 + dx];
        }
    }
    if (TOKOUT) {
        const int bb = bc >> 7;
#pragma unroll
        for (int r = 0; r < ROWS; r++) {
            int y = r0 + r;
            int wid_ = bb * 256 + (y >> 4) * 16 + (x >> 4);
            int t = (y & 15) * 16 + (x & 15);
            *reinterpret_cast<unsigned short*>(
                &out[((size_t)(wid_ * 256 + t)) * 128 + c]) = f2bu(acc[r]);
        }
    } else {
        bf16* ob = out + (size_t)bc * HWP + (size_t)r0 * 256 + x;
#pragma unroll
        for (int r = 0; r < ROWS; r++)
            *reinterpret_cast<unsigned short*>(&ob[r * 256]) = f2bu(acc[r]);
    }
}

// out = gelu_exact(g) * ca + res ; ALL token-major bf16, fully vectorized.
// grid (4096, NB): thread handles one 8-channel segment of one token.
__global__ LB void k_tmp(const bf16* __restrict__ g, const float* __restrict__ ca,
                         const bf16* __restrict__ res, bf16* __restrict__ out) {
    const int i = blockIdx.x * 256 + threadIdx.x;   // [0, 65536*16)
    const int b = blockIdx.y;
    const int c0 = (i & 15) * 8;
    const size_t base = ((size_t)b * HWP + (i >> 4)) * 128 + c0;
    float gv[8], rv[8], fv[8];
    ld8(g + base, gv);
    ld8(res + base, rv);
    const float* cab = ca + b * 128 + c0;
#pragma unroll
    for (int j = 0; j < 8; j++) {
        float gl = 0.5f * gv[j] * (1.f + erff(gv[j] * 0.70710678118654752f));
        fv[j] = gl * cab[j] + rv[j];
    }
    st8(out + base, fv);
}

// ---------------------------------------------------------------------------
extern "C" void kernel_launch(void* const* d_in, const int* in_sizes, int n_in,
                              void* d_out, int out_size, void* d_ws, size_t ws_size,
                              hipStream_t stream) {
    const float* x     = (const float*)d_in[0];
    const float* cg    = (const float*)d_in[1];
    const float* gum   = (const float*)d_in[2];
    const float* pv_w  = (const float*)d_in[3];
    const float* pv_b  = (const float*)d_in[4];
    const float* pq_w  = (const float*)d_in[5];
    const float* pq_b  = (const float*)d_in[6];
    const float* pk_w  = (const float*)d_in[7];
    const float* pk_b  = (const float*)d_in[8];
    const float* cs1_w = (const float*)d_in[9];
    const float* cs1_b = (const float*)d_in[10];
    const float* cs2_w = (const float*)d_in[11];
    const float* cs2_b = (const float*)d_in[12];
    const float* cs3_w = (const float*)d_in[13];
    const float* cs3_b = (const float*)d_in[14];
    const float* po_w  = (const float*)d_in[15];
    const float* po_b  = (const float*)d_in[16];
    const float* rin_w = (const float*)d_in[17];
    const float* rin_b = (const float*)d_in[18];
    const float* ro1_w = (const float*)d_in[19];
    const float* ro1_b = (const float*)d_in[20];
    const float* ro2_w = (const float*)d_in[21];
    const float* ro2_b = (const float*)d_in[22];
    const float* rm1_w = (const float*)d_in[23];
    const float* rm1_b = (const float*)d_in[24];
    const float* rm2_w = (const float*)d_in[25];
    const float* rm2_b = (const float*)d_in[26];
    const float* rca_w = (const float*)d_in[27];
    const float* rca_b = (const float*)d_in[28];
    const float* rsa_w = (const float*)d_in[29];
    const float* rsa_b = (const float*)d_in[30];

    char* wsp = (char*)d_ws;
    size_t off = 0;
    auto alloc = [&](size_t bytes) -> char* {
        char* p = wsp + off;
        off += (bytes + 255) & ~(size_t)255;
        return p;
    };
    const size_t NELT = (size_t)NB * 128 * HWP;  // 33.5M elems
    float* v    = (float*)alloc(NELT * 4);                  // fp32: pv out (control path)
    float* f    = (float*)alloc((size_t)NB * 32 * HWP * 4); // fp32
    bf16*  xw   = (bf16*)alloc(NELT * 2);                   // warp out (tok); attn wout (tok)
    bf16*  qb   = (bf16*)alloc(NELT * 2);                   // q (tok); dw2 out (tok)
    bf16*  kb   = (bf16*)alloc(NELT * 2);                   // k (tok); cs1 out (pix); tmp out (tok)
    float* offs = (float*)alloc((size_t)NB * 2 * HWP * 4);
    float* sab  = (float*)alloc((size_t)NB * HWP * 4);
    float* fpix = (float*)alloc((size_t)NB * HWP * 4);
    float* fmean= (float*)alloc(NB * 32 * 4);
    float* cab  = (float*)alloc(NB * 128 * 4);
    float* mk   = (float*)alloc(NB * 256 * 4);
    bf16*  dw1o = (bf16*)v;   // v's space reused after attention (dw1 out, pix)
    (void)ws_size; (void)in_sizes; (void)n_in; (void)out_size;

    float* out = (float*)d_out;
    dim3 gpix(256, NB);

    k_pvconv<<<dim3(1024, NB), 256, 0, stream>>>(x, pv_w, pv_b, v);
    k_rin<<<gpix, 256, 0, stream>>>(v, cg, rin_w, rin_b, f);
    k_offsets<<<gpix, 256, 0, stream>>>(f, ro1_w, ro1_b, ro2_w, ro2_b, offs);
    k_fpix<<<gpix, 256, 0, stream>>>(f, fpix);
    k_fmean<<<dim3(NB * 32), 256, 0, stream>>>(f, fmean);
    k_ca<<<dim3(NB), 128, 0, stream>>>(fmean, rca_w, rca_b, cab);
    k_sa<<<gpix, 256, 0, stream>>>(f, rsa_w, rsa_b, sab);
    k_mask<<<dim3(NB), 256, 0, stream>>>(fpix, gum, rm1_w, rm1_b, rm2_w, rm2_b, mk);
    k_warp<<<gpix, 256, 0, stream>>>(x, offs, xw);
    k_wingemm<0, bf16><<<dim3(NB * 256), 256, 0, stream>>>(xw, pq_w, pq_b, mk, qb);
    k_wingemm<0, bf16><<<dim3(NB * 256), 256, 0, stream>>>(xw, pk_w, pk_b, mk, kb);
    k_attn<<<dim3(NB * 256), 256, 0, stream>>>(qb, kb, v, sab, mk, xw);
    k_wingemm<1, bf16><<<dim3(NB * 256), 256, 0, stream>>>(xw, cs1_w, cs1_b, mk, kb);
    k_dwconv5<1, false><<<dim3(256 / 32, NB * 128), 256, 0, stream>>>(kb, cs2_w, cs2_b, dw1o);
    k_dwconv5<3, true><<<dim3(256 / 32, NB * 128), 256, 0, stream>>>(dw1o, cs3_w, cs3_b, qb);
    k_tmp<<<dim3(4096, NB), 256, 0, stream>>>(qb, cab, xw, kb);
    k_wingemm<2, float><<<dim3(NB * 256), 256, 0, stream>>>(kb, po_w, po_b, mk, out);
}

// Round 4
// 1255.516 us; speedup vs baseline: 2.6548x; 1.0689x over previous
//
#include <hip/hip_runtime.h>
#include <hip/hip_bf16.h>

// CAMixer forward, MI355X. Round 7 (resubmit; round-3 bench was an infra
// failure, not a kernel fault). k_warp gather rewrite: thread = (pixel,
// 8ch-octet) -> 16x wave count; taps pair-loaded as float2 (border remapped
// x0=min(floor,254)/wx=sx-x0, exactly equivalent to reference clamp).
// Rest identical to passing round 6.

typedef __hip_bfloat16 bf16;
using short8 = __attribute__((ext_vector_type(8))) short;   // 8 bf16 = 4 VGPR
using f32x4  = __attribute__((ext_vector_type(4))) float;   // MFMA C/D

#define HWP 65536   // H*W
#define NB  4       // batch
#define LB  __launch_bounds__(256)

__device__ __forceinline__ float u2f(unsigned short s) {
    return __uint_as_float(((unsigned int)s) << 16);
}
__device__ __forceinline__ float b2f(bf16 v) { return __bfloat162float(v); }
__device__ __forceinline__ unsigned short f2bu(float x) {
    bf16 h = __float2bfloat16(x);
    return *reinterpret_cast<unsigned short*>(&h);
}
__device__ __forceinline__ float leaky(float x) { return x > 0.f ? x : 0.2f * x; }
__device__ __forceinline__ float sigmoidf(float x) { return 1.f / (1.f + __expf(-x)); }

struct __attribute__((aligned(4))) f2u { float x, y; };   // 4B-aligned float2

__device__ __forceinline__ void ld8(const float* p, float* f) {
    float4 u0 = *reinterpret_cast<const float4*>(p);
    float4 u1 = *reinterpret_cast<const float4*>(p + 4);
    f[0] = u0.x; f[1] = u0.y; f[2] = u0.z; f[3] = u0.w;
    f[4] = u1.x; f[5] = u1.y; f[6] = u1.z; f[7] = u1.w;
}
__device__ __forceinline__ void ld8(const bf16* p, float* f) {
    uint4 u = *reinterpret_cast<const uint4*>(p);
    const unsigned short* s = reinterpret_cast<const unsigned short*>(&u);
#pragma unroll
    for (int i = 0; i < 8; i++) f[i] = u2f(s[i]);
}
__device__ __forceinline__ void st8(bf16* p, const float* f) {
    uint4 r;
    r.x = (unsigned)f2bu(f[0]) | ((unsigned)f2bu(f[1]) << 16);
    r.y = (unsigned)f2bu(f[2]) | ((unsigned)f2bu(f[3]) << 16);
    r.z = (unsigned)f2bu(f[4]) | ((unsigned)f2bu(f[5]) << 16);
    r.w = (unsigned)f2bu(f[6]) | ((unsigned)f2bu(f[7]) << 16);
    *reinterpret_cast<uint4*>(p) = r;
}
__device__ __forceinline__ void stv4(float* p, float a, float b, float c, float d) {
    float4 v; v.x = a; v.y = b; v.z = c; v.w = d;
    *reinterpret_cast<float4*>(p) = v;
}
__device__ __forceinline__ void stv4(bf16* p, float a, float b, float c, float d) {
    uint2 r;
    r.x = (unsigned)f2bu(a) | ((unsigned)f2bu(b) << 16);
    r.y = (unsigned)f2bu(c) | ((unsigned)f2bu(d) << 16);
    *reinterpret_cast<uint2*>(p) = r;
}

// ---------------------------------------------------------------------------
// pv: 1x1 conv fp32->fp32, pixel-major (control path; stays fp32 VALU).
// ---------------------------------------------------------------------------
__global__ LB void k_pvconv(const float* __restrict__ in, const float* __restrict__ w,
                            const float* __restrict__ bias, float* __restrict__ out) {
    __shared__ float Wt[32][128];   // current k-chunk, [k][oc]
    __shared__ float Xs[32][64];
    const int tid = threadIdx.x;
    const int p0 = blockIdx.x * 64;
    const int b = blockIdx.y;
    const int pg = tid & 15;
    const int og = tid >> 4;
    float acc[4][8];
#pragma unroll
    for (int i = 0; i < 4; i++)
#pragma unroll
        for (int j = 0; j < 8; j++) acc[i][j] = 0.f;
    const float* inb = in + ((size_t)b * 128) * HWP + p0;
    for (int k0 = 0; k0 < 128; k0 += 32) {
        __syncthreads();
#pragma unroll
        for (int it = 0; it < 4; it++) {
            int jj = tid + it * 256;          // [0,1024)
            int oc = jj & 127, kq = jj >> 7;  // kq 0..7
            float4 wv = *reinterpret_cast<const float4*>(w + oc * 128 + k0 + kq * 4);
            Wt[kq * 4 + 0][oc] = wv.x;
            Wt[kq * 4 + 1][oc] = wv.y;
            Wt[kq * 4 + 2][oc] = wv.z;
            Wt[kq * 4 + 3][oc] = wv.w;
        }
        {
            int row = tid >> 3;
            int col0 = (tid & 7) * 8;
            float t8[8];
            ld8(inb + (size_t)(k0 + row) * HWP + col0, t8);
#pragma unroll
            for (int i = 0; i < 8; i++) Xs[row][col0 + i] = t8[i];
        }
        __syncthreads();
#pragma unroll
        for (int kk = 0; kk < 32; kk++) {
            float a0 = Xs[kk][pg * 4 + 0];
            float a1 = Xs[kk][pg * 4 + 1];
            float a2 = Xs[kk][pg * 4 + 2];
            float a3 = Xs[kk][pg * 4 + 3];
            const float* wr = &Wt[kk][og * 8];
#pragma unroll
            for (int j = 0; j < 8; j++) {
                float wv = wr[j];
                acc[0][j] += a0 * wv;
                acc[1][j] += a1 * wv;
                acc[2][j] += a2 * wv;
                acc[3][j] += a3 * wv;
            }
        }
    }
#pragma unroll
    for (int j = 0; j < 8; j++) {
        int oc = og * 8 + j;
        float bv = bias[oc];
        float* po = out + ((size_t)(b * 128 + oc)) * HWP + p0 + pg * 4;
        stv4(po, acc[0][j] + bv, acc[1][j] + bv, acc[2][j] + bv, acc[3][j] + bv);
    }
}

// ---------------------------------------------------------------------------
// rin: f = leaky(conv1x1(cond)); cond = [v(128) | cond_global | cy | cx]
// ---------------------------------------------------------------------------
__global__ LB void k_rin(const float* __restrict__ v, const float* __restrict__ cg,
                         const float* __restrict__ w, const float* __restrict__ bias,
                         float* __restrict__ f) {
    __shared__ float Wl[131][36];
    __shared__ float Bs[32];
    const int tid = threadIdx.x;
    for (int i = tid; i < 131 * 32; i += 256) {
        int ic = i >> 5, oc = i & 31;
        Wl[ic][oc] = w[oc * 131 + ic];
    }
    if (tid < 32) Bs[tid] = bias[tid];
    __syncthreads();
    const int p = blockIdx.x * 256 + tid;
    const int b = blockIdx.y;
    float acc[32];
#pragma unroll
    for (int o = 0; o < 32; o++) acc[o] = 0.f;
    const float* vb = v + ((size_t)b * 128) * HWP + p;
    for (int ic = 0; ic < 128; ic++) {
        float a = vb[(size_t)ic * HWP];
#pragma unroll
        for (int o = 0; o < 32; o++) acc[o] += a * Wl[ic][o];
    }
    float a128 = cg[(size_t)b * HWP + p];
    int y = p >> 8, x = p & 255;
    float a129 = -1.f + (2.f / 15.f) * (float)(y & 15);
    float a130 = -1.f + (2.f / 15.f) * (float)(x & 15);
#pragma unroll
    for (int o = 0; o < 32; o++) {
        float r = acc[o] + a128 * Wl[128][o] + a129 * Wl[129][o] + a130 * Wl[130][o] + Bs[o];
        f[((size_t)(b * 32 + o)) * HWP + p] = leaky(r);
    }
}

// offsets = conv1x1(leaky(conv1x1(f))): 32 -> 16 -> 2
__global__ LB void k_offsets(const float* __restrict__ f, const float* __restrict__ w1,
                             const float* __restrict__ b1, const float* __restrict__ w2,
                             const float* __restrict__ b2, float* __restrict__ offs) {
    __shared__ float W1[32][16];
    __shared__ float W2[16][2];
    __shared__ float B1[16];
    __shared__ float B2[2];
    const int tid = threadIdx.x;
    for (int i = tid; i < 512; i += 256) {
        int ic = i >> 4, o = i & 15;
        W1[ic][o] = w1[o * 32 + ic];
    }
    if (tid < 32) { int h = tid >> 1, o = tid & 1; W2[h][o] = w2[o * 16 + h]; }
    if (tid < 16) B1[tid] = b1[tid];
    if (tid < 2) B2[tid] = b2[tid];
    __syncthreads();
    const int p = blockIdx.x * 256 + tid;
    const int b = blockIdx.y;
    float h[16];
#pragma unroll
    for (int o = 0; o < 16; o++) h[o] = B1[o];
    for (int ic = 0; ic < 32; ic++) {
        float a = f[((size_t)(b * 32 + ic)) * HWP + p];
#pragma unroll
        for (int o = 0; o < 16; o++) h[o] += a * W1[ic][o];
    }
    float o0 = B2[0], o1 = B2[1];
#pragma unroll
    for (int o = 0; o < 16; o++) {
        float hv = leaky(h[o]);
        o0 += hv * W2[o][0];
        o1 += hv * W2[o][1];
    }
    offs[((size_t)(b * 2 + 0)) * HWP + p] = o0;
    offs[((size_t)(b * 2 + 1)) * HWP + p] = o1;
}

__global__ LB void k_fpix(const float* __restrict__ f, float* __restrict__ fpix) {
    const int p = blockIdx.x * 256 + threadIdx.x;
    const int b = blockIdx.y;
    float s = 0.f;
    for (int c = 0; c < 32; c++) s += f[((size_t)(b * 32 + c)) * HWP + p];
    fpix[(size_t)b * HWP + p] = s * (1.f / 32.f);
}

__global__ LB void k_fmean(const float* __restrict__ f, float* __restrict__ fmean) {
    const int b = blockIdx.x >> 5, c = blockIdx.x & 31;
    const float* base = f + ((size_t)(b * 32 + c)) * HWP;
    float s = 0.f;
    for (int i = threadIdx.x; i < HWP; i += 256) s += base[i];
    __shared__ float red[256];
    red[threadIdx.x] = s;
    __syncthreads();
    for (int st = 128; st > 0; st >>= 1) {
        if (threadIdx.x < st) red[threadIdx.x] += red[threadIdx.x + st];
        __syncthreads();
    }
    if (threadIdx.x == 0) fmean[b * 32 + c] = red[0];
}

__global__ LB void k_ca(const float* __restrict__ fmean, const float* __restrict__ w,
                        const float* __restrict__ bias, float* __restrict__ ca) {
    const int b = blockIdx.x, oc = threadIdx.x;
    float acc = bias[oc];
    for (int ic = 0; ic < 32; ic++)
        acc += w[oc * 32 + ic] * fmean[b * 32 + ic] * (1.f / 65536.f);
    ca[b * 128 + oc] = sigmoidf(acc);
}

__global__ LB void k_sa(const float* __restrict__ f, const float* __restrict__ w,
                        const float* __restrict__ bias, float* __restrict__ sa) {
    __shared__ float Wl[32][9];
    __shared__ float bs;
    const int tid = threadIdx.x;
    for (int i = tid; i < 288; i += 256) Wl[i / 9][i % 9] = w[i];
    if (tid == 0) bs = bias[0];
    __syncthreads();
    const int p = blockIdx.x * 256 + tid;
    const int b = blockIdx.y;
    const int y = p >> 8, x = p & 255;
    float acc = bs;
    for (int ic = 0; ic < 32; ic++) {
        const float* fb = f + ((size_t)(b * 32 + ic)) * HWP;
#pragma unroll
        for (int dy = 0; dy < 3; dy++) {
            int yy = y + dy - 1;
            if ((unsigned)yy >= 256u) continue;
#pragma unroll
            for (int dx = 0; dx < 3; dx++) {
                int xx = x + dx - 1;
                if ((unsigned)xx >= 256u) continue;
                acc += fb[yy * 256 + xx] * Wl[ic][dy * 3 + dx];
            }
        }
    }
    sa[(size_t)b * HWP + p] = sigmoidf(acc);
}

// gumbel hard mask per window; thread = window
__global__ LB void k_mask(const float* __restrict__ fpix, const float* __restrict__ gum,
                          const float* __restrict__ w1, const float* __restrict__ b1,
                          const float* __restrict__ w2, const float* __restrict__ b2,
                          float* __restrict__ mask) {
    __shared__ float W1[256][16];
    __shared__ float W2[2][16];
    __shared__ float B1[16];
    __shared__ float B2[2];
    const int tid = threadIdx.x;
    for (int i = tid; i < 4096; i += 256) {
        int o = i >> 8, e = i & 255;
        W1[e][o] = w1[o * 256 + e];
    }
    if (tid < 32) W2[tid >> 4][tid & 15] = w2[tid];
    if (tid < 16) B1[tid] = b1[tid];
    if (tid < 2) B2[tid] = b2[tid];
    __syncthreads();
    const int wid = blockIdx.x * 256 + tid;
    const int b = wid >> 8, n = wid & 255;
    const int wy = n >> 4, wx = n & 15;
    const float* fp = fpix + (size_t)b * HWP + (wy * 16) * 256 + wx * 16;
    float h[16];
#pragma unroll
    for (int o = 0; o < 16; o++) h[o] = B1[o];
    for (int e = 0; e < 256; e++) {
        float mv = fp[(e >> 4) * 256 + (e & 15)];
#pragma unroll
        for (int o = 0; o < 16; o++) h[o] += mv * W1[e][o];
    }
    float l0 = B2[0], l1 = B2[1];
#pragma unroll
    for (int o = 0; o < 16; o++) {
        float hv = leaky(h[o]);
        l0 += hv * W2[0][o];
        l1 += hv * W2[1][o];
    }
    float mx = fmaxf(l0, l1);
    float e0 = __expf(l0 - mx), e1 = __expf(l1 - mx);
    float inv = 1.f / (e0 + e1);
    float p0 = e0 * inv, p1 = e1 * inv;
    float u0 = gum[wid * 2 + 0], u1 = gum[wid * 2 + 1];
    float g0 = -logf(-logf(u0 + 1e-10f) + 1e-10f);
    float g1 = -logf(-logf(u1 + 1e-10f) + 1e-10f);
    mask[wid] = (p0 + g0 >= p1 + g1) ? 1.f : 0.f;
}

// ---------------------------------------------------------------------------
// bilinear flow warp, border clamp; TOKEN-MAJOR bf16 out: xw[(wid*256+t)][c].
// Thread = (pixel, 8ch octet); lanes = 64 consecutive pixels of the same
// octet (coalesced); taps pair-loaded as float2 via border remap
// x0=min(floor(sx),254), wx=sx-x0 (identical to reference clamp semantics).
// Grid (HWP/64, 4, NB); wave count 16x round 6.
// ---------------------------------------------------------------------------
__global__ LB void k_warp(const float* __restrict__ x, const float* __restrict__ offs,
                          bf16* __restrict__ xw) {
    const int tid = threadIdx.x;
    const int p = blockIdx.x * 64 + (tid & 63);
    const int oct = blockIdx.y * 4 + (tid >> 6);
    const int b = blockIdx.z;
    const int y = p >> 8, xc = p & 255;
    float fx = offs[((size_t)(b * 2 + 0)) * HWP + p];
    float fy = offs[((size_t)(b * 2 + 1)) * HWP + p];
    float sx = fminf(fmaxf((float)xc + fx, 0.f), 255.f);
    float sy = fminf(fmaxf((float)y + fy, 0.f), 255.f);
    int x0 = min((int)sx, 254);           // floor for sx>=0
    int y0 = min((int)sy, 254);
    float wx = sx - (float)x0;            // in [0,1]
    float wy = sy - (float)y0;
    float w00 = (1.f - wx) * (1.f - wy), w01 = wx * (1.f - wy);
    float w10 = (1.f - wx) * wy, w11 = wx * wy;
    const float* base = x + ((size_t)(b * 128 + oct * 8)) * HWP + y0 * 256 + x0;
    float fv[8];
#pragma unroll
    for (int j = 0; j < 8; j++) {
        f2u r0 = *reinterpret_cast<const f2u*>(base + (size_t)j * HWP);
        f2u r1 = *reinterpret_cast<const f2u*>(base + (size_t)j * HWP + 256);
        fv[j] = r0.x * w00 + r0.y * w01 + r1.x * w10 + r1.y * w11;
    }
    const int wid = b * 256 + (y >> 4) * 16 + (xc >> 4);
    const int t = (y & 15) * 16 + (xc & 15);
    st8(xw + ((size_t)(wid * 256 + t)) * 128 + oct * 8, fv);
}

// ---------------------------------------------------------------------------
// MFMA per-window GEMM: out[256tok x 128oc] = A[256tok x 128k] * W^T + bias.
// MODE 0: token-major bf16 out, skip masked windows (qkproj)
// MODE 1: pixel-major bf16 out (cs1)
// MODE 2: pixel-major fp32 out (po)
// ---------------------------------------------------------------------------
template <int MODE, typename OutT>
__global__ __launch_bounds__(256, 1) void k_wingemm(
        const bf16* __restrict__ A, const float* __restrict__ w,
        const float* __restrict__ bias, const float* __restrict__ mask,
        OutT* __restrict__ outp) {
    const int wid = blockIdx.x;
    if (MODE == 0) {
        if (mask[wid] < 0.5f) return;   // block-uniform
    }
    __shared__ unsigned short Wl[128][136];  // [oc][k], rows 272B (16B-mult)
    __shared__ float Bs[128];
    const int tid = threadIdx.x;
    for (int j = tid; j < 4096; j += 256) {
        int oc = j >> 5, k4 = (j & 31) * 4;
        float4 wv = *reinterpret_cast<const float4*>(w + oc * 128 + k4);
        uint2 r;
        r.x = (unsigned)f2bu(wv.x) | ((unsigned)f2bu(wv.y) << 16);
        r.y = (unsigned)f2bu(wv.z) | ((unsigned)f2bu(wv.w) << 16);
        *reinterpret_cast<uint2*>(&Wl[oc][k4]) = r;
    }
    if (tid < 128) Bs[tid] = bias[tid];
    const int wv_ = tid >> 6, lane = tid & 63, quad = lane >> 4, lid = lane & 15;
    const bf16* arow = A + (size_t)wid * 256 * 128;
    short8 af[4][4];
#pragma unroll
    for (int mt = 0; mt < 4; mt++)
#pragma unroll
        for (int kf = 0; kf < 4; kf++)
            af[mt][kf] = *reinterpret_cast<const short8*>(
                arow + (size_t)(wv_ * 64 + mt * 16 + lid) * 128 + kf * 32 + quad * 8);
    __syncthreads();
    f32x4 acc[4][8];
#pragma unroll
    for (int mt = 0; mt < 4; mt++)
#pragma unroll
        for (int cf = 0; cf < 8; cf++)
#pragma unroll
            for (int i = 0; i < 4; i++) acc[mt][cf][i] = 0.f;
#pragma unroll
    for (int cf = 0; cf < 8; cf++) {
        short8 wf[4];
#pragma unroll
        for (int kf = 0; kf < 4; kf++)
            wf[kf] = *reinterpret_cast<const short8*>(&Wl[cf * 16 + lid][kf * 32 + quad * 8]);
#pragma unroll
        for (int mt = 0; mt < 4; mt++)
#pragma unroll
            for (int kf = 0; kf < 4; kf++)
                acc[mt][cf] = __builtin_amdgcn_mfma_f32_16x16x32_bf16(af[mt][kf], wf[kf], acc[mt][cf], 0, 0, 0);
    }
    if (MODE == 0) {
        bf16* ob = (bf16*)outp;
#pragma unroll
        for (int cf = 0; cf < 8; cf++) {
            float bv = Bs[cf * 16 + lid];
#pragma unroll
            for (int mt = 0; mt < 4; mt++)
#pragma unroll
                for (int i = 0; i < 4; i++) {
                    int row = wv_ * 64 + mt * 16 + quad * 4 + i;
                    *reinterpret_cast<unsigned short*>(
                        &ob[((size_t)(wid * 256 + row)) * 128 + cf * 16 + lid]) =
                        f2bu(acc[mt][cf][i] + bv);
                }
        }
    } else {
        const int b = wid >> 8, n = wid & 255;
        const int wy = n >> 4, wx = n & 15;
#pragma unroll
        for (int cf = 0; cf < 8; cf++) {
            int oc = cf * 16 + lid;
            float bv = Bs[oc];
            OutT* plane = outp + ((size_t)(b * 128 + oc)) * HWP;
#pragma unroll
            for (int mt = 0; mt < 4; mt++) {
                int t0 = wv_ * 64 + mt * 16 + quad * 4;   // 4-aligned token
                int ty = t0 >> 4, tx = t0 & 15;
                int px = (wy * 16 + ty) * 256 + wx * 16 + tx;
                stv4(plane + px, acc[mt][cf][0] + bv, acc[mt][cf][1] + bv,
                     acc[mt][cf][2] + bv, acc[mt][cf][3] + bv);
            }
        }
    }
}

// ---------------------------------------------------------------------------
// MFMA flash attention (token-major q/k in, token-major wout, pixel-major v).
// ---------------------------------------------------------------------------
__global__ __launch_bounds__(256, 1) void k_attn(
        const bf16* __restrict__ qbuf, const bf16* __restrict__ kbuf,
        const float* __restrict__ v, const float* __restrict__ sa,
        const float* __restrict__ mask, bf16* __restrict__ wout) {
    const int wid = blockIdx.x;
    const int b = wid >> 8, n = wid & 255;
    const int wy = n >> 4, wx = n & 15;
    const int tid = threadIdx.x;
    const int pixbase = (wy * 16) * 256 + wx * 16;
    const float* vb = v + ((size_t)b * 128) * HWP;
    if (mask[wid] < 0.5f) {        // block-uniform branch
        const int t = tid;
        const int pix = pixbase + (t >> 4) * 256 + (t & 15);
        float s = sa[(size_t)b * HWP + pix];
        bf16* orow = wout + ((size_t)(wid * 256 + t)) * 128;
        for (int c0 = 0; c0 < 128; c0 += 8) {
            float fv[8];
#pragma unroll
            for (int i = 0; i < 8; i++) fv[i] = vb[(size_t)(c0 + i) * HWP + pix] * s;
            st8(orow + c0, fv);
        }
        return;
    }
    __shared__ unsigned short Pl[4][64][72];   // per-wave P relayout buffer
    __shared__ unsigned short Vt[128][72];     // V^T tile: [c][j], bf16
    const int w = tid >> 6, lane = tid & 63, quad = lane >> 4, lid = lane & 15;
    const bf16* qwin = qbuf + (size_t)wid * 256 * 128;
    const bf16* kwin = kbuf + (size_t)wid * 256 * 128;
    short8 qf[4][4];
#pragma unroll
    for (int mt = 0; mt < 4; mt++)
#pragma unroll
        for (int kf = 0; kf < 4; kf++)
            qf[mt][kf] = *reinterpret_cast<const short8*>(
                qwin + (size_t)(w * 64 + mt * 16 + lid) * 128 + kf * 32 + quad * 8);

    f32x4 O[4][8];
#pragma unroll
    for (int mt = 0; mt < 4; mt++)
#pragma unroll
        for (int cf = 0; cf < 8; cf++)
#pragma unroll
            for (int i = 0; i < 4; i++) O[mt][cf][i] = 0.f;
    float mrow[4][4], lrow[4][4];
#pragma unroll
    for (int mt = 0; mt < 4; mt++)
#pragma unroll
        for (int i = 0; i < 4; i++) { mrow[mt][i] = -1e30f; lrow[mt][i] = 0.f; }

    for (int j0 = 0; j0 < 256; j0 += 64) {
        __syncthreads();   // prev iter's Vt reads complete
        {
            int c = tid >> 1, jh = (tid & 1) * 32;
            const float* vcol = vb + (size_t)c * HWP + pixbase;
#pragma unroll
            for (int jj = 0; jj < 32; jj += 2) {
                int t1 = j0 + jh + jj, t2 = t1 + 1;
                float v1 = vcol[(t1 >> 4) * 256 + (t1 & 15)];
                float v2 = vcol[(t2 >> 4) * 256 + (t2 & 15)];
                unsigned u = (unsigned)f2bu(v1) | ((unsigned)f2bu(v2) << 16);
                *reinterpret_cast<unsigned*>(&Vt[c][jh + jj]) = u;
            }
        }
        f32x4 sacc[4][4];
#pragma unroll
        for (int nt = 0; nt < 4; nt++) {
            short8 kfr[4];
#pragma unroll
            for (int kf = 0; kf < 4; kf++)
                kfr[kf] = *reinterpret_cast<const short8*>(
                    kwin + (size_t)(j0 + nt * 16 + lid) * 128 + kf * 32 + quad * 8);
#pragma unroll
            for (int mt = 0; mt < 4; mt++) {
                f32x4 acc;
                acc[0] = 0.f; acc[1] = 0.f; acc[2] = 0.f; acc[3] = 0.f;
#pragma unroll
                for (int kf = 0; kf < 4; kf++)
                    acc = __builtin_amdgcn_mfma_f32_16x16x32_bf16(qf[mt][kf], kfr[kf], acc, 0, 0, 0);
                sacc[mt][nt] = acc;
            }
        }
        float alpha[4][4];
#pragma unroll
        for (int mt = 0; mt < 4; mt++)
#pragma unroll
            for (int i = 0; i < 4; i++) {
                float mx = sacc[mt][0][i];
                mx = fmaxf(mx, sacc[mt][1][i]);
                mx = fmaxf(mx, sacc[mt][2][i]);
                mx = fmaxf(mx, sacc[mt][3][i]);
                mx = fmaxf(mx, __shfl_xor(mx, 1));
                mx = fmaxf(mx, __shfl_xor(mx, 2));
                mx = fmaxf(mx, __shfl_xor(mx, 4));
                mx = fmaxf(mx, __shfl_xor(mx, 8));
                float mn = fmaxf(mrow[mt][i], mx);
                alpha[mt][i] = __expf(mrow[mt][i] - mn);
                mrow[mt][i] = mn;
            }
#pragma unroll
        for (int mt = 0; mt < 4; mt++) {
            float ps[4] = {0.f, 0.f, 0.f, 0.f};
#pragma unroll
            for (int nt = 0; nt < 4; nt++)
#pragma unroll
                for (int i = 0; i < 4; i++) {
                    float p = __expf(sacc[mt][nt][i] - mrow[mt][i]);
                    ps[i] += p;
                    Pl[w][mt * 16 + quad * 4 + i][nt * 16 + lid] = f2bu(p);
                }
#pragma unroll
            for (int i = 0; i < 4; i++) {
                float rs = ps[i];
                rs += __shfl_xor(rs, 1);
                rs += __shfl_xor(rs, 2);
                rs += __shfl_xor(rs, 4);
                rs += __shfl_xor(rs, 8);
                lrow[mt][i] = lrow[mt][i] * alpha[mt][i] + rs;
            }
        }
#pragma unroll
        for (int mt = 0; mt < 4; mt++)
#pragma unroll
            for (int cf = 0; cf < 8; cf++)
#pragma unroll
                for (int i = 0; i < 4; i++) O[mt][cf][i] *= alpha[mt][i];
        __syncthreads();   // Vt staged (cross-wave), Pl written
        short8 pa[4][2];
#pragma unroll
        for (int mt = 0; mt < 4; mt++)
#pragma unroll
            for (int kq = 0; kq < 2; kq++)
                pa[mt][kq] = *reinterpret_cast<const short8*>(
                    &Pl[w][mt * 16 + lid][kq * 32 + quad * 8]);
#pragma unroll
        for (int cf = 0; cf < 8; cf++) {
            short8 vf0 = *reinterpret_cast<const short8*>(&Vt[cf * 16 + lid][quad * 8]);
            short8 vf1 = *reinterpret_cast<const short8*>(&Vt[cf * 16 + lid][32 + quad * 8]);
#pragma unroll
            for (int mt = 0; mt < 4; mt++) {
                O[mt][cf] = __builtin_amdgcn_mfma_f32_16x16x32_bf16(pa[mt][0], vf0, O[mt][cf], 0, 0, 0);
                O[mt][cf] = __builtin_amdgcn_mfma_f32_16x16x32_bf16(pa[mt][1], vf1, O[mt][cf], 0, 0, 0);
            }
        }
    }
#pragma unroll
    for (int mt = 0; mt < 4; mt++) {
        float inv[4];
#pragma unroll
        for (int i = 0; i < 4; i++) inv[i] = 1.f / lrow[mt][i];
#pragma unroll
        for (int cf = 0; cf < 8; cf++)
#pragma unroll
            for (int i = 0; i < 4; i++) {
                int row = w * 64 + mt * 16 + quad * 4 + i;
                int col = cf * 16 + lid;
                *reinterpret_cast<unsigned short*>(
                    &wout[((size_t)(wid * 256 + row)) * 128 + col]) = f2bu(O[mt][cf][i] * inv[i]);
            }
    }
}

// ---------------------------------------------------------------------------
// depthwise 5x5, pad = 2*DIL, dilation DIL (bf16 -> bf16). LDS-strip tiled.
// TOKOUT: write token-major [tok][c].
// ---------------------------------------------------------------------------
template <int DIL, bool TOKOUT>
__global__ LB void k_dwconv5(const bf16* __restrict__ in, const float* __restrict__ w,
                             const float* __restrict__ bias, bf16* __restrict__ out) {
    constexpr int HLO = 2 * DIL;          // halo rows/cols each side (2 or 6)
    constexpr int ROWS = 32;              // output rows per block
    constexpr int NR = ROWS + 2 * HLO;    // staged rows (36 or 44)
    __shared__ unsigned short Ls[NR][272];  // cols: [0..7]=pad, [8..263]=img, [264..271]=pad
    const int tid = threadIdx.x;
    const int bc = blockIdx.y;            // b*128 + c
    const int c = bc & 127;
    const int r0 = blockIdx.x * ROWS;
    const bf16* ib = in + (size_t)bc * HWP;
    for (int i = tid; i < NR * 32; i += 256) {
        int row = i >> 5, seg = i & 31;
        int y = r0 - HLO + row;
        uint4 val;
        if ((unsigned)y < 256u) {
            val = *reinterpret_cast<const uint4*>(ib + y * 256 + seg * 8);
        } else {
            val.x = 0u; val.y = 0u; val.z = 0u; val.w = 0u;
        }
        *reinterpret_cast<uint4*>(&Ls[row][8 + seg * 8]) = val;
    }
    for (int i = tid; i < NR * 2; i += 256) {
        int row = i >> 1;
        uint4 zz; zz.x = 0u; zz.y = 0u; zz.z = 0u; zz.w = 0u;
        *reinterpret_cast<uint4*>(&Ls[row][(i & 1) ? 264 : 0]) = zz;
    }
    float W[25];
#pragma unroll
    for (int i = 0; i < 25; i++) W[i] = w[c * 25 + i];
    const float bv = bias[c];
    __syncthreads();
    const int x = tid;                    // thread = column
    float acc[ROWS];
#pragma unroll
    for (int r = 0; r < ROWS; r++) acc[r] = bv;
#pragma unroll
    for (int iy = 0; iy < NR; iy++) {
        float v5[5];
#pragma unroll
        for (int dx = 0; dx < 5; dx++)
            v5[dx] = u2f(Ls[iy][8 + x + (dx - 2) * DIL]);
#pragma unroll
        for (int dy = 0; dy < 5; dy++) {
            const int ro = iy - HLO + (2 - dy) * DIL;   // compile-time after unroll
            if (ro < 0 || ro >= ROWS) continue;
#pragma unroll
            for (int dx = 0; dx < 5; dx++)
                acc[ro] += v5[dx] * W[dy * 5 + dx];
        }
    }
    if (TOKOUT) {
        const int bb = bc >> 7;
#pragma unroll
        for (int r = 0; r < ROWS; r++) {
            int y = r0 + r;
            int wid_ = bb * 256 + (y >> 4) * 16 + (x >> 4);
            int t = (y & 15) * 16 + (x & 15);
            *reinterpret_cast<unsigned short*>(
                &out[((size_t)(wid_ * 256 + t)) * 128 + c]) = f2bu(acc[r]);
        }
    } else {
        bf16* ob = out + (size_t)bc * HWP + (size_t)r0 * 256 + x;
#pragma unroll
        for (int r = 0; r < ROWS; r++)
            *reinterpret_cast<unsigned short*>(&ob[r * 256]) = f2bu(acc[r]);
    }
}

// out = gelu_exact(g) * ca + res ; ALL token-major bf16, fully vectorized.
__global__ LB void k_tmp(const bf16* __restrict__ g, const float* __restrict__ ca,
                         const bf16* __restrict__ res, bf16* __restrict__ out) {
    const int i = blockIdx.x * 256 + threadIdx.x;   // [0, 65536*16)
    const int b = blockIdx.y;
    const int c0 = (i & 15) * 8;
    const size_t base = ((size_t)b * HWP + (i >> 4)) * 128 + c0;
    float gv[8], rv[8], fv[8];
    ld8(g + base, gv);
    ld8(res + base, rv);
    const float* cab = ca + b * 128 + c0;
#pragma unroll
    for (int j = 0; j < 8; j++) {
        float gl = 0.5f * gv[j] * (1.f + erff(gv[j] * 0.70710678118654752f));
        fv[j] = gl * cab[j] + rv[j];
    }
    st8(out + base, fv);
}

// ---------------------------------------------------------------------------
extern "C" void kernel_launch(void* const* d_in, const int* in_sizes, int n_in,
                              void* d_out, int out_size, void* d_ws, size_t ws_size,
                              hipStream_t stream) {
    const float* x     = (const float*)d_in[0];
    const float* cg    = (const float*)d_in[1];
    const float* gum   = (const float*)d_in[2];
    const float* pv_w  = (const float*)d_in[3];
    const float* pv_b  = (const float*)d_in[4];
    const float* pq_w  = (const float*)d_in[5];
    const float* pq_b  = (const float*)d_in[6];
    const float* pk_w  = (const float*)d_in[7];
    const float* pk_b  = (const float*)d_in[8];
    const float* cs1_w = (const float*)d_in[9];
    const float* cs1_b = (const float*)d_in[10];
    const float* cs2_w = (const float*)d_in[11];
    const float* cs2_b = (const float*)d_in[12];
    const float* cs3_w = (const float*)d_in[13];
    const float* cs3_b = (const float*)d_in[14];
    const float* po_w  = (const float*)d_in[15];
    const float* po_b  = (const float*)d_in[16];
    const float* rin_w = (const float*)d_in[17];
    const float* rin_b = (const float*)d_in[18];
    const float* ro1_w = (const float*)d_in[19];
    const float* ro1_b = (const float*)d_in[20];
    const float* ro2_w = (const float*)d_in[21];
    const float* ro2_b = (const float*)d_in[22];
    const float* rm1_w = (const float*)d_in[23];
    const float* rm1_b = (const float*)d_in[24];
    const float* rm2_w = (const float*)d_in[25];
    const float* rm2_b = (const float*)d_in[26];
    const float* rca_w = (const float*)d_in[27];
    const float* rca_b = (const float*)d_in[28];
    const float* rsa_w = (const float*)d_in[29];
    const float* rsa_b = (const float*)d_in[30];

    char* wsp = (char*)d_ws;
    size_t off = 0;
    auto alloc = [&](size_t bytes) -> char* {
        char* p = wsp + off;
        off += (bytes + 255) & ~(size_t)255;
        return p;
    };
    const size_t NELT = (size_t)NB * 128 * HWP;  // 33.5M elems
    float* v    = (float*)alloc(NELT * 4);                  // fp32: pv out (control path)
    float* f    = (float*)alloc((size_t)NB * 32 * HWP * 4); // fp32
    bf16*  xw   = (bf16*)alloc(NELT * 2);                   // warp out (tok); attn wout (tok)
    bf16*  qb   = (bf16*)alloc(NELT * 2);                   // q (tok); dw2 out (tok)
    bf16*  kb   = (bf16*)alloc(NELT * 2);                   // k (tok); cs1 out (pix); tmp out (tok)
    float* offs = (float*)alloc((size_t)NB * 2 * HWP * 4);
    float* sab  = (float*)alloc((size_t)NB * HWP * 4);
    float* fpix = (float*)alloc((size_t)NB * HWP * 4);
    float* fmean= (float*)alloc(NB * 32 * 4);
    float* cab  = (float*)alloc(NB * 128 * 4);
    float* mk   = (float*)alloc(NB * 256 * 4);
    bf16*  dw1o = (bf16*)v;   // v's space reused after attention (dw1 out, pix)
    (void)ws_size; (void)in_sizes; (void)n_in; (void)out_size;

    float* out = (float*)d_out;
    dim3 gpix(256, NB);

    k_pvconv<<<dim3(1024, NB), 256, 0, stream>>>(x, pv_w, pv_b, v);
    k_rin<<<gpix, 256, 0, stream>>>(v, cg, rin_w, rin_b, f);
    k_offsets<<<gpix, 256, 0, stream>>>(f, ro1_w, ro1_b, ro2_w, ro2_b, offs);
    k_fpix<<<gpix, 256, 0, stream>>>(f, fpix);
    k_fmean<<<dim3(NB * 32), 256, 0, stream>>>(f, fmean);
    k_ca<<<dim3(NB), 128, 0, stream>>>(fmean, rca_w, rca_b, cab);
    k_sa<<<gpix, 256, 0, stream>>>(f, rsa_w, rsa_b, sab);
    k_mask<<<dim3(NB), 256, 0, stream>>>(fpix, gum, rm1_w, rm1_b, rm2_w, rm2_b, mk);
    k_warp<<<dim3(1024, 4, NB), 256, 0, stream>>>(x, offs, xw);
    k_wingemm<0, bf16><<<dim3(NB * 256), 256, 0, stream>>>(xw, pq_w, pq_b, mk, qb);
    k_wingemm<0, bf16><<<dim3(NB * 256), 256, 0, stream>>>(xw, pk_w, pk_b, mk, kb);
    k_attn<<<dim3(NB * 256), 256, 0, stream>>>(qb, kb, v, sab, mk, xw);
    k_wingemm<1, bf16><<<dim3(NB * 256), 256, 0, stream>>>(xw, cs1_w, cs1_b, mk, kb);
    k_dwconv5<1, false><<<dim3(256 / 32, NB * 128), 256, 0, stream>>>(kb, cs2_w, cs2_b, dw1o);
    k_dwconv5<3, true><<<dim3(256 / 32, NB * 128), 256, 0, stream>>>(dw1o, cs3_w, cs3_b, qb);
    k_tmp<<<dim3(4096, NB), 256, 0, stream>>>(qb, cab, xw, kb);
    k_wingemm<2, float><<<dim3(NB * 256), 256, 0, stream>>>(kb, po_w, po_b, mk, out);
}